// Round 1
// 233.242 us; speedup vs baseline: 1.0027x; 1.0027x over previous
//
#include <hip/hip_runtime.h>

// ---------- constants ----------
#define PP    300
#define DD    1024
#define NOUT  604          // (150+1)*4
#define NROWS 19200        // 64*300
// output element offsets (fp32 elements)
#define OFF_PAIR  76800
#define OFF_BBOX  5836800  // 76800 + 64*300*300

typedef unsigned short u16;
typedef __attribute__((ext_vector_type(8))) short bf16x8;
typedef __attribute__((ext_vector_type(4))) float f32x4;

#define GLOBAL_AS __attribute__((address_space(1)))
#define LDS_AS    __attribute__((address_space(3)))

__device__ inline u16 f2bf(float f) {
    unsigned u = __float_as_uint(f);
    return (u16)((u + 0x7fffu + ((u >> 16) & 1u)) >> 16);
}
__device__ inline float dot4(float4 a, float4 b) {
    return fmaf(a.x, b.x, fmaf(a.y, b.y, fmaf(a.z, b.z, a.w * b.w)));
}
__device__ inline float sigmoidf(float z) { return 1.f / (1.f + __expf(-z)); }

// ---------- kernel 1: transpose+pad W_bbox (1024x604 f32) -> Bt (640x1024 bf16) ----------
__global__ void k_transpose(const float* __restrict__ W, u16* __restrict__ Bt) {
    __shared__ float tile[32][33];
    int k0 = blockIdx.x * 32;
    int n0 = blockIdx.y * 32;
    int tx = threadIdx.x;           // 0..31
    int ty = threadIdx.y;           // 0..7
#pragma unroll
    for (int i = 0; i < 4; ++i) {
        int k = k0 + ty + i * 8;
        int n = n0 + tx;
        tile[ty + i * 8][tx] = (n < NOUT) ? W[(size_t)k * NOUT + n] : 0.f;
    }
    __syncthreads();
#pragma unroll
    for (int i = 0; i < 4; ++i) {
        int n = n0 + ty + i * 8;
        int k = k0 + tx;
        Bt[(size_t)n * DD + k] = f2bf(tile[tx][ty + i * 8]);
    }
}

// ---------- kernel 2: v = W_theta @ Wc  (Wc = W_pair[2048:3072]) ----------
__global__ void k_vtheta(const float* __restrict__ Wt, const float* __restrict__ Wpair,
                         float* __restrict__ v) {
    int wave = threadIdx.x >> 6, lane = threadIdx.x & 63;
    int k = blockIdx.x * 4 + wave;                // 0..1023
    const float4* row = (const float4*)(Wt + (size_t)k * DD);
    const float4* wc  = (const float4*)(Wpair + 2 * DD);
    float s = 0.f;
#pragma unroll
    for (int i = 0; i < 4; ++i) s += dot4(row[i * 64 + lane], wc[i * 64 + lane]);
#pragma unroll
    for (int off = 32; off; off >>= 1) s += __shfl_down(s, off, 64);
    if (lane == 0) v[k] = s;
}

// ---------- kernel 3: per-batch scalars ----------
__global__ void k_scalars(const float* __restrict__ relation, const float* __restrict__ subject,
                          const float* __restrict__ obj, const float* __restrict__ btheta,
                          const float* __restrict__ Wpair, const float* __restrict__ bpair,
                          const float* __restrict__ Wcls, const float* __restrict__ bcls,
                          const float* __restrict__ v,
                          float* __restrict__ relt, float* __restrict__ subc,
                          float* __restrict__ objc) {
    __shared__ float red[4];
    int wave = threadIdx.x >> 6, lane = threadIdx.x & 63;
    int b = blockIdx.x;
    const float4* aa;
    const float4* bb;
    if (wave == 0)      { aa = (const float4*)(relation + (size_t)b * DD); bb = (const float4*)v; }
    else if (wave == 1) { aa = (const float4*)(subject + (size_t)b * DD);  bb = (const float4*)(Wcls + DD); }
    else if (wave == 2) { aa = (const float4*)(obj + (size_t)b * DD);      bb = (const float4*)(Wcls + DD); }
    else                { aa = (const float4*)btheta;                      bb = (const float4*)(Wpair + 2 * DD); }
    float s = 0.f;
#pragma unroll
    for (int i = 0; i < 4; ++i) s += dot4(aa[i * 64 + lane], bb[i * 64 + lane]);
#pragma unroll
    for (int off = 32; off; off >>= 1) s += __shfl_down(s, off, 64);
    if (lane == 0) red[wave] = s;
    __syncthreads();
    if (threadIdx.x == 0) {
        relt[b] = red[0] + red[3] + bpair[0];
        subc[b] = red[1] + bcls[0];
        objc[b] = red[2] + bcls[0];
    }
}

// ---------- kernel 4: per-row dots + fp32 x_subj/x_obj outputs (+ optional bf16 x copy) ----------
template<int WB>
__global__ __launch_bounds__(256) void k_rows(
        const float* __restrict__ x, const float* __restrict__ Wpair,
        const float* __restrict__ Wcls,
        const float* __restrict__ relt, const float* __restrict__ subc,
        const float* __restrict__ objc,
        float* __restrict__ colv, float* __restrict__ rowp,
        float* __restrict__ sarr, float* __restrict__ oarr,
        float* __restrict__ out, u16* __restrict__ xb) {
    int wave = threadIdx.x >> 6, lane = threadIdx.x & 63;
    int r = blockIdx.x * 4 + wave;                // 0..19199
    const float4* xr = (const float4*)(x + (size_t)r * DD);
    const float4* wa = (const float4*)(Wpair);
    const float4* wb = (const float4*)(Wpair + DD);
    const float4* w1 = (const float4*)(Wcls);
    float ca = 0.f, cb = 0.f, cw = 0.f;
#pragma unroll
    for (int i = 0; i < 4; ++i) {
        int idx = i * 64 + lane;
        float4 xv = xr[idx];
        ca += dot4(xv, wa[idx]);
        cb += dot4(xv, wb[idx]);
        cw += dot4(xv, w1[idx]);
        if (WB) {
            // truncate fp32 -> bf16 (identical numerics to the GEMM's previous in-kernel perm)
            unsigned lo = __builtin_amdgcn_perm(__float_as_uint(xv.y), __float_as_uint(xv.x), 0x07060302u);
            unsigned hi = __builtin_amdgcn_perm(__float_as_uint(xv.w), __float_as_uint(xv.z), 0x07060302u);
            *(uint2*)(xb + (size_t)r * DD + idx * 4) = make_uint2(lo, hi);
        }
    }
#pragma unroll
    for (int off = 32; off; off >>= 1) {
        ca += __shfl_down(ca, off, 64);
        cb += __shfl_down(cb, off, 64);
        cw += __shfl_down(cw, off, 64);
    }
    if (lane == 0) {
        int b = r / 300;
        float s = sigmoidf(cw + subc[b]);
        float o = sigmoidf(cw + objc[b]);
        colv[r] = ca;
        rowp[r] = cb + relt[b];
        sarr[r] = s;
        oarr[r] = o;
        ((float2*)out)[r]         = make_float2(1.f - s, s);   // x_subj pair (fp32)
        ((float2*)out)[NROWS + r] = make_float2(1.f - o, o);   // x_obj pair (fp32)
    }
}

// ---------- kernel 5: pair_score (fp32), 10 rows per block ----------
#define PR_ROWS 10
__global__ __launch_bounds__(192) void k_pair(
        const float* __restrict__ rowp, const float* __restrict__ colv,
        const float* __restrict__ sarr, const float* __restrict__ oarr,
        float* __restrict__ pout) {
    __shared__ float cb_s[300];
    __shared__ float ob_s[300];
    int blk = blockIdx.x;               // 0..1919
    int b = blk / 30;
    int chunk = blk - b * 30;           // 0..29
    int r0 = b * 300 + chunk * PR_ROWS;
    int tid = threadIdx.x;
    for (int j = tid; j < 300; j += 192) {
        cb_s[j] = colv[b * 300 + j];
        ob_s[j] = oarr[b * 300 + j];
    }
    __syncthreads();
    if (tid < 150) {
        float c0 = cb_s[2 * tid],     c1 = cb_s[2 * tid + 1];
        float o0 = ob_s[2 * tid],     o1 = ob_s[2 * tid + 1];
#pragma unroll
        for (int rr = 0; rr < PR_ROWS; ++rr) {
            int r = r0 + rr;
            float rp = rowp[r];
            float ss = sarr[r];
            float p0 = sigmoidf(rp + c0) * o0 * ss;
            float p1 = sigmoidf(rp + c1) * o1 * ss;
            ((float2*)(pout + (size_t)r * 300))[tid] = make_float2(p0, p1);
        }
    }
}

// ---------- kernel 6a: bbox GEMM, bf16 A from workspace (m97 structure) ----------
#define BKK 64
__global__ __launch_bounds__(256) void k_gemm_bf(
        const u16* __restrict__ xb, const u16* __restrict__ bt,
        const float* __restrict__ bias, float* __restrict__ out) {
    __shared__ u16 As[128 * BKK] __attribute__((aligned(16)));
    __shared__ u16 Bs[128 * BKK] __attribute__((aligned(16)));

    int bid = blockIdx.x;
    int xcd = bid & 7;
    int rest = bid >> 3;
    int n_t = rest % 5;
    int m_t = (rest / 5) * 8 + xcd;
    if (m_t >= 150) return;

    int tid = threadIdx.x;
    int wave = tid >> 6;
    int lane = tid & 63;
    int wr = wave >> 1, wc = wave & 1;
    int quad = lane >> 4;
    int l16 = lane & 15;

    f32x4 acc[4][4] = {};

    const u16* a_base = xb + (size_t)m_t * 128 * DD;
    const u16* b_base = bt + (size_t)n_t * 128 * DD;
    int s_row = lane >> 3;      // 0..7
    int s_c16 = lane & 7;       // 16B chunk (8 bf16)

    for (int k0 = 0; k0 < DD; k0 += BKK) {
        // both tiles via 16B global_load_lds (wave-uniform LDS base, lane*16 implicit)
#pragma unroll
        for (int q = 0; q < 4; ++q) {
            int rowblk = q * 32 + wave * 8;
            const u16* ga = a_base + (size_t)(rowblk + s_row) * DD + k0 + s_c16 * 8;
            __builtin_amdgcn_global_load_lds((const GLOBAL_AS unsigned int*)ga,
                                             (LDS_AS unsigned int*)(As + rowblk * BKK),
                                             16, 0, 0);
            const u16* gb = b_base + (size_t)(rowblk + s_row) * DD + k0 + s_c16 * 8;
            __builtin_amdgcn_global_load_lds((const GLOBAL_AS unsigned int*)gb,
                                             (LDS_AS unsigned int*)(Bs + rowblk * BKK),
                                             16, 0, 0);
        }
        __syncthreads();
#pragma unroll
        for (int kk = 0; kk < BKK; kk += 32) {
            bf16x8 af[4], bfv[4];
#pragma unroll
            for (int f = 0; f < 4; ++f) {
                int m = wr * 64 + f * 16 + l16;
                af[f] = *(const bf16x8*)(As + m * BKK + kk + quad * 8);
                int n = wc * 64 + f * 16 + l16;
                bfv[f] = *(const bf16x8*)(Bs + n * BKK + kk + quad * 8);
            }
#pragma unroll
            for (int fi = 0; fi < 4; ++fi)
#pragma unroll
                for (int fj = 0; fj < 4; ++fj)
                    acc[fi][fj] = __builtin_amdgcn_mfma_f32_16x16x32_bf16(
                        af[fi], bfv[fj], acc[fi][fj], 0, 0, 0);
        }
        __syncthreads();
    }

#pragma unroll
    for (int fj = 0; fj < 4; ++fj) {
        int col = n_t * 128 + wc * 64 + fj * 16 + l16;
        if (col < NOUT) {
            float bia = bias[col];
#pragma unroll
            for (int fi = 0; fi < 4; ++fi) {
#pragma unroll
                for (int rg = 0; rg < 4; ++rg) {
                    int row = m_t * 128 + wr * 64 + fi * 16 + quad * 4 + rg;
                    out[(size_t)row * NOUT + col] = acc[fi][fj][rg] + bia;
                }
            }
        }
    }
}

// ---------- kernel 6b: fallback GEMM, fp32 A converted in-kernel (previous verified path) ----------
__global__ __launch_bounds__(256) void k_gemm(
        const float* __restrict__ x, const u16* __restrict__ bt,
        const float* __restrict__ bias, float* __restrict__ out) {
    __shared__ u16 As[128 * BKK] __attribute__((aligned(16)));
    __shared__ u16 Bs[128 * BKK] __attribute__((aligned(16)));

    int bid = blockIdx.x;
    int xcd = bid & 7;
    int rest = bid >> 3;
    int n_t = rest % 5;
    int m_t = (rest / 5) * 8 + xcd;
    if (m_t >= 150) return;

    int tid = threadIdx.x;
    int wave = tid >> 6;
    int lane = tid & 63;
    int wr = wave >> 1, wc = wave & 1;
    int quad = lane >> 4;
    int l16 = lane & 15;

    f32x4 acc[4][4] = {};

    const float* a_base = x  + (size_t)m_t * 128 * DD;
    const u16*   b_base = bt + (size_t)n_t * 128 * DD;
    int s_row = lane >> 3;
    int s_c16 = lane & 7;
    int arow8 = tid >> 4;
    int acol4 = tid & 15;

    for (int k0 = 0; k0 < DD; k0 += BKK) {
#pragma unroll
        for (int q = 0; q < 4; ++q) {
            int rowblk = q * 32 + wave * 8;
            const u16* gb = b_base + (size_t)(rowblk + s_row) * DD + k0 + s_c16 * 8;
            __builtin_amdgcn_global_load_lds((const GLOBAL_AS unsigned int*)gb,
                                             (LDS_AS unsigned int*)(Bs + rowblk * BKK),
                                             16, 0, 0);
        }
#pragma unroll
        for (int it = 0; it < 8; ++it) {
            int row = it * 16 + arow8;
            float4 av = *(const float4*)(a_base + (size_t)row * DD + k0 + acol4 * 4);
            unsigned lo = __builtin_amdgcn_perm(__float_as_uint(av.y), __float_as_uint(av.x), 0x07060302u);
            unsigned hi = __builtin_amdgcn_perm(__float_as_uint(av.w), __float_as_uint(av.z), 0x07060302u);
            *(uint2*)(As + row * BKK + acol4 * 4) = make_uint2(lo, hi);
        }
        __syncthreads();
#pragma unroll
        for (int kk = 0; kk < BKK; kk += 32) {
            bf16x8 af[4], bfv[4];
#pragma unroll
            for (int f = 0; f < 4; ++f) {
                int m = wr * 64 + f * 16 + l16;
                af[f] = *(const bf16x8*)(As + m * BKK + kk + quad * 8);
                int n = wc * 64 + f * 16 + l16;
                bfv[f] = *(const bf16x8*)(Bs + n * BKK + kk + quad * 8);
            }
#pragma unroll
            for (int fi = 0; fi < 4; ++fi)
#pragma unroll
                for (int fj = 0; fj < 4; ++fj)
                    acc[fi][fj] = __builtin_amdgcn_mfma_f32_16x16x32_bf16(
                        af[fi], bfv[fj], acc[fi][fj], 0, 0, 0);
        }
        __syncthreads();
    }

#pragma unroll
    for (int fj = 0; fj < 4; ++fj) {
        int col = n_t * 128 + wc * 64 + fj * 16 + l16;
        if (col < NOUT) {
            float bia = bias[col];
#pragma unroll
            for (int fi = 0; fi < 4; ++fi) {
#pragma unroll
                for (int rg = 0; rg < 4; ++rg) {
                    int row = m_t * 128 + wr * 64 + fi * 16 + quad * 4 + rg;
                    out[(size_t)row * NOUT + col] = acc[fi][fj][rg] + bia;
                }
            }
        }
    }
}

extern "C" void kernel_launch(void* const* d_in, const int* in_sizes, int n_in,
                              void* d_out, int out_size, void* d_ws, size_t ws_size,
                              hipStream_t stream) {
    // ---- input binding by element counts (proven equivalent to dict order) ----
    const void* P[12] = {};
    int sv[3] = {-1, -1, -1}; int nsv = 0;
    int sc[2] = {-1, -1};     int nsc = 0;
    for (int i = 0; i < n_in; ++i) {
        switch (in_sizes[i]) {
            case 19660800: P[0]  = d_in[i]; break;
            case 65536:    if (nsv < 3) sv[nsv++] = i; break;
            case 1048576:  P[4]  = d_in[i]; break;
            case 1024:     P[5]  = d_in[i]; break;
            case 3072:     P[6]  = d_in[i]; break;
            case 1:        if (nsc < 2) sc[nsc++] = i; break;
            case 2048:     P[8]  = d_in[i]; break;
            case 618496:   P[10] = d_in[i]; break;
            case 604:      P[11] = d_in[i]; break;
            default: break;
        }
    }
    bool alpha = (n_in == 12 && in_sizes[0] == 618496);
    if (alpha) {
        P[2] = d_in[sv[0]]; P[3] = d_in[sv[1]]; P[1] = d_in[sv[2]];
        P[9] = d_in[sc[0]]; P[7] = d_in[sc[1]];
    } else {
        P[1] = d_in[sv[0]]; P[2] = d_in[sv[1]]; P[3] = d_in[sv[2]];
        P[7] = d_in[sc[0]]; P[9] = d_in[sc[1]];
    }
    const float* x        = (const float*)P[0];
    const float* subject  = (const float*)P[1];
    const float* obj      = (const float*)P[2];
    const float* relation = (const float*)P[3];
    const float* W_theta  = (const float*)P[4];
    const float* b_theta  = (const float*)P[5];
    const float* W_pair   = (const float*)P[6];
    const float* b_pair   = (const float*)P[7];
    const float* W_cls    = (const float*)P[8];
    const float* b_cls    = (const float*)P[9];
    const float* W_bbox   = (const float*)P[10];
    const float* b_bbox   = (const float*)P[11];
    float* out = (float*)d_out;

    // ws layout
    char* ws = (char*)d_ws;
    float* v    = (float*)(ws + 0);         // 1024 f32
    float* relt = (float*)(ws + 4096);      // 64 f32
    float* subc = (float*)(ws + 4352);      // 64 f32
    float* objc = (float*)(ws + 4608);      // 64 f32
    float* colv = (float*)(ws + 4864);      // 19200 f32
    float* rowp = (float*)(ws + 81664);     // 19200 f32
    float* sarr = (float*)(ws + 158464);    // 19200 f32
    float* oarr = (float*)(ws + 235264);    // 19200 f32 (end 312,064)
    u16*   Bt   = (u16*)(ws + 312064);      // 640*1024 bf16 = 1,310,720 B (end 1,622,784)
    u16*   Xb   = (u16*)(ws + 1622784);     // 19200*1024 bf16 = 39,321,600 B (end 40,944,384)

    const size_t WS_NEED_BF16 = 40944384;
    bool big_ws = (ws_size >= WS_NEED_BF16);

    k_transpose<<<dim3(32, 20), dim3(32, 8), 0, stream>>>(W_bbox, Bt);
    k_vtheta<<<256, 256, 0, stream>>>(W_theta, W_pair, v);
    k_scalars<<<64, 256, 0, stream>>>(relation, subject, obj, b_theta, W_pair, b_pair,
                                      W_cls, b_cls, v, relt, subc, objc);
    if (big_ws) {
        k_rows<1><<<4800, 256, 0, stream>>>(x, W_pair, W_cls, relt, subc, objc,
                                            colv, rowp, sarr, oarr, out, Xb);
    } else {
        k_rows<0><<<4800, 256, 0, stream>>>(x, W_pair, W_cls, relt, subc, objc,
                                            colv, rowp, sarr, oarr, out, nullptr);
    }
    k_pair<<<1920, 192, 0, stream>>>(rowp, colv, sarr, oarr, out + OFF_PAIR);
    if (big_ws) {
        k_gemm_bf<<<760, 256, 0, stream>>>(Xb, Bt, b_bbox, out + OFF_BBOX);
    } else {
        k_gemm<<<760, 256, 0, stream>>>(x, Bt, b_bbox, out + OFF_BBOX);
    }
}

// Round 2
// 224.693 us; speedup vs baseline: 1.0408x; 1.0380x over previous
//
#include <hip/hip_runtime.h>

// ---------- constants ----------
#define PP    300
#define DD    1024
#define NOUT  604          // (150+1)*4
#define NROWS 19200        // 64*300
// output element offsets (fp32 elements)
#define OFF_PAIR  76800
#define OFF_BBOX  5836800  // 76800 + 64*300*300

typedef unsigned short u16;
typedef __attribute__((ext_vector_type(8))) short bf16x8;
typedef __attribute__((ext_vector_type(4))) float f32x4;

#define GLOBAL_AS __attribute__((address_space(1)))
#define LDS_AS    __attribute__((address_space(3)))

__device__ inline u16 f2bf(float f) {
    unsigned u = __float_as_uint(f);
    return (u16)((u + 0x7fffu + ((u >> 16) & 1u)) >> 16);
}
__device__ inline float dot4(float4 a, float4 b) {
    return fmaf(a.x, b.x, fmaf(a.y, b.y, fmaf(a.z, b.z, a.w * b.w)));
}
__device__ inline float sigmoidf(float z) { return 1.f / (1.f + __expf(-z)); }

// ---------- kernel 1: transpose+pad W_bbox (1024x604 f32) -> Bt (640x1024 bf16) ----------
__global__ void k_transpose(const float* __restrict__ W, u16* __restrict__ Bt) {
    __shared__ float tile[32][33];
    int k0 = blockIdx.x * 32;
    int n0 = blockIdx.y * 32;
    int tx = threadIdx.x;           // 0..31
    int ty = threadIdx.y;           // 0..7
#pragma unroll
    for (int i = 0; i < 4; ++i) {
        int k = k0 + ty + i * 8;
        int n = n0 + tx;
        tile[ty + i * 8][tx] = (n < NOUT) ? W[(size_t)k * NOUT + n] : 0.f;
    }
    __syncthreads();
#pragma unroll
    for (int i = 0; i < 4; ++i) {
        int n = n0 + ty + i * 8;
        int k = k0 + tx;
        Bt[(size_t)n * DD + k] = f2bf(tile[tx][ty + i * 8]);
    }
}

// ---------- kernel 2: v = W_theta @ Wc  (Wc = W_pair[2048:3072]) ----------
__global__ void k_vtheta(const float* __restrict__ Wt, const float* __restrict__ Wpair,
                         float* __restrict__ v) {
    int wave = threadIdx.x >> 6, lane = threadIdx.x & 63;
    int k = blockIdx.x * 4 + wave;                // 0..1023
    const float4* row = (const float4*)(Wt + (size_t)k * DD);
    const float4* wc  = (const float4*)(Wpair + 2 * DD);
    float s = 0.f;
#pragma unroll
    for (int i = 0; i < 4; ++i) s += dot4(row[i * 64 + lane], wc[i * 64 + lane]);
#pragma unroll
    for (int off = 32; off; off >>= 1) s += __shfl_down(s, off, 64);
    if (lane == 0) v[k] = s;
}

// ---------- kernel 3: per-batch scalars ----------
__global__ void k_scalars(const float* __restrict__ relation, const float* __restrict__ subject,
                          const float* __restrict__ obj, const float* __restrict__ btheta,
                          const float* __restrict__ Wpair, const float* __restrict__ bpair,
                          const float* __restrict__ Wcls, const float* __restrict__ bcls,
                          const float* __restrict__ v,
                          float* __restrict__ relt, float* __restrict__ subc,
                          float* __restrict__ objc) {
    __shared__ float red[4];
    int wave = threadIdx.x >> 6, lane = threadIdx.x & 63;
    int b = blockIdx.x;
    const float4* aa;
    const float4* bb;
    if (wave == 0)      { aa = (const float4*)(relation + (size_t)b * DD); bb = (const float4*)v; }
    else if (wave == 1) { aa = (const float4*)(subject + (size_t)b * DD);  bb = (const float4*)(Wcls + DD); }
    else if (wave == 2) { aa = (const float4*)(obj + (size_t)b * DD);      bb = (const float4*)(Wcls + DD); }
    else                { aa = (const float4*)btheta;                      bb = (const float4*)(Wpair + 2 * DD); }
    float s = 0.f;
#pragma unroll
    for (int i = 0; i < 4; ++i) s += dot4(aa[i * 64 + lane], bb[i * 64 + lane]);
#pragma unroll
    for (int off = 32; off; off >>= 1) s += __shfl_down(s, off, 64);
    if (lane == 0) red[wave] = s;
    __syncthreads();
    if (threadIdx.x == 0) {
        relt[b] = red[0] + red[3] + bpair[0];
        subc[b] = red[1] + bcls[0];
        objc[b] = red[2] + bcls[0];
    }
}

// ---------- kernel 4: per-row dots + fp32 x_subj/x_obj outputs (+ optional bf16 x copy) ----------
template<int WB>
__global__ __launch_bounds__(256) void k_rows(
        const float* __restrict__ x, const float* __restrict__ Wpair,
        const float* __restrict__ Wcls,
        const float* __restrict__ relt, const float* __restrict__ subc,
        const float* __restrict__ objc,
        float* __restrict__ colv, float* __restrict__ rowp,
        float* __restrict__ sarr, float* __restrict__ oarr,
        float* __restrict__ out, u16* __restrict__ xb) {
    int wave = threadIdx.x >> 6, lane = threadIdx.x & 63;
    int r = blockIdx.x * 4 + wave;                // 0..19199
    const float4* xr = (const float4*)(x + (size_t)r * DD);
    const float4* wa = (const float4*)(Wpair);
    const float4* wb = (const float4*)(Wpair + DD);
    const float4* w1 = (const float4*)(Wcls);
    float ca = 0.f, cb = 0.f, cw = 0.f;
#pragma unroll
    for (int i = 0; i < 4; ++i) {
        int idx = i * 64 + lane;
        float4 xv = xr[idx];
        ca += dot4(xv, wa[idx]);
        cb += dot4(xv, wb[idx]);
        cw += dot4(xv, w1[idx]);
        if (WB) {
            // truncate fp32 -> bf16 (identical numerics to the GEMM's previous in-kernel perm)
            unsigned lo = __builtin_amdgcn_perm(__float_as_uint(xv.y), __float_as_uint(xv.x), 0x07060302u);
            unsigned hi = __builtin_amdgcn_perm(__float_as_uint(xv.w), __float_as_uint(xv.z), 0x07060302u);
            *(uint2*)(xb + (size_t)r * DD + idx * 4) = make_uint2(lo, hi);
        }
    }
#pragma unroll
    for (int off = 32; off; off >>= 1) {
        ca += __shfl_down(ca, off, 64);
        cb += __shfl_down(cb, off, 64);
        cw += __shfl_down(cw, off, 64);
    }
    if (lane == 0) {
        int b = r / 300;
        float s = sigmoidf(cw + subc[b]);
        float o = sigmoidf(cw + objc[b]);
        colv[r] = ca;
        rowp[r] = cb + relt[b];
        sarr[r] = s;
        oarr[r] = o;
        ((float2*)out)[r]         = make_float2(1.f - s, s);   // x_subj pair (fp32)
        ((float2*)out)[NROWS + r] = make_float2(1.f - o, o);   // x_obj pair (fp32)
    }
}

// ---------- kernel 5: pair_score (fp32), 10 rows per block ----------
#define PR_ROWS 10
__global__ __launch_bounds__(192) void k_pair(
        const float* __restrict__ rowp, const float* __restrict__ colv,
        const float* __restrict__ sarr, const float* __restrict__ oarr,
        float* __restrict__ pout) {
    __shared__ float cb_s[300];
    __shared__ float ob_s[300];
    int blk = blockIdx.x;               // 0..1919
    int b = blk / 30;
    int chunk = blk - b * 30;           // 0..29
    int r0 = b * 300 + chunk * PR_ROWS;
    int tid = threadIdx.x;
    for (int j = tid; j < 300; j += 192) {
        cb_s[j] = colv[b * 300 + j];
        ob_s[j] = oarr[b * 300 + j];
    }
    __syncthreads();
    if (tid < 150) {
        float c0 = cb_s[2 * tid],     c1 = cb_s[2 * tid + 1];
        float o0 = ob_s[2 * tid],     o1 = ob_s[2 * tid + 1];
#pragma unroll
        for (int rr = 0; rr < PR_ROWS; ++rr) {
            int r = r0 + rr;
            float rp = rowp[r];
            float ss = sarr[r];
            float p0 = sigmoidf(rp + c0) * o0 * ss;
            float p1 = sigmoidf(rp + c1) * o1 * ss;
            ((float2*)(pout + (size_t)r * 300))[tid] = make_float2(p0, p1);
        }
    }
}

// ---------- kernel 6a: bbox GEMM, bf16 A from workspace, XOR-swizzled LDS (T2) ----------
// LDS tiles are [128 rows][64 bf16] = row stride 128 B = exactly 32 banks.
// Linear layout => 16-way bank conflict on every ds_read_b128 (measured 9.216M conflict
// cycles). Fix per rule #21: global_load_lds writes linearly, so the swizzle is applied
// as inverse-permuted GLOBAL source chunk + same XOR on the LDS read (involution).
// LDS[row][c16] holds global chunk (c16 ^ (row&7)).
#define BKK 64
__global__ __launch_bounds__(256) void k_gemm_bf(
        const u16* __restrict__ xb, const u16* __restrict__ bt,
        const float* __restrict__ bias, float* __restrict__ out) {
    __shared__ u16 As[128 * BKK] __attribute__((aligned(16)));
    __shared__ u16 Bs[128 * BKK] __attribute__((aligned(16)));

    int bid = blockIdx.x;
    int xcd = bid & 7;
    int rest = bid >> 3;
    int n_t = rest % 5;
    int m_t = (rest / 5) * 8 + xcd;
    if (m_t >= 150) return;

    int tid = threadIdx.x;
    int wave = tid >> 6;
    int lane = tid & 63;
    int wr = wave >> 1, wc = wave & 1;
    int quad = lane >> 4;
    int l16 = lane & 15;

    f32x4 acc[4][4] = {};

    const u16* a_base = xb + (size_t)m_t * 128 * DD;
    const u16* b_base = bt + (size_t)n_t * 128 * DD;
    int s_row = lane >> 3;              // 0..7 (row within 8-row staging block)
    int s_c16 = (lane & 7) ^ s_row;     // pre-swizzled source 16B-chunk (XOR involution)

    for (int k0 = 0; k0 < DD; k0 += BKK) {
        // both tiles via 16B global_load_lds; LDS dest linear, source pre-swizzled
#pragma unroll
        for (int q = 0; q < 4; ++q) {
            int rowblk = q * 32 + wave * 8;
            const u16* ga = a_base + (size_t)(rowblk + s_row) * DD + k0 + s_c16 * 8;
            __builtin_amdgcn_global_load_lds((const GLOBAL_AS unsigned int*)ga,
                                             (LDS_AS unsigned int*)(As + rowblk * BKK),
                                             16, 0, 0);
            const u16* gb = b_base + (size_t)(rowblk + s_row) * DD + k0 + s_c16 * 8;
            __builtin_amdgcn_global_load_lds((const GLOBAL_AS unsigned int*)gb,
                                             (LDS_AS unsigned int*)(Bs + rowblk * BKK),
                                             16, 0, 0);
        }
        __syncthreads();
#pragma unroll
        for (int kk = 0; kk < BKK; kk += 32) {
            bf16x8 af[4], bfv[4];
            // 16B-chunk index within the row: (kk>>3) + quad, XOR row&7 (= l16&7)
            int cx = (((kk >> 3) + quad) ^ (l16 & 7)) * 8;
#pragma unroll
            for (int f = 0; f < 4; ++f) {
                int m = wr * 64 + f * 16 + l16;
                af[f] = *(const bf16x8*)(As + m * BKK + cx);
                int n = wc * 64 + f * 16 + l16;
                bfv[f] = *(const bf16x8*)(Bs + n * BKK + cx);
            }
#pragma unroll
            for (int fi = 0; fi < 4; ++fi)
#pragma unroll
                for (int fj = 0; fj < 4; ++fj)
                    acc[fi][fj] = __builtin_amdgcn_mfma_f32_16x16x32_bf16(
                        af[fi], bfv[fj], acc[fi][fj], 0, 0, 0);
        }
        __syncthreads();
    }

#pragma unroll
    for (int fj = 0; fj < 4; ++fj) {
        int col = n_t * 128 + wc * 64 + fj * 16 + l16;
        if (col < NOUT) {
            float bia = bias[col];
#pragma unroll
            for (int fi = 0; fi < 4; ++fi) {
#pragma unroll
                for (int rg = 0; rg < 4; ++rg) {
                    int row = m_t * 128 + wr * 64 + fi * 16 + quad * 4 + rg;
                    out[(size_t)row * NOUT + col] = acc[fi][fj][rg] + bia;
                }
            }
        }
    }
}

// ---------- kernel 6b: fallback GEMM, fp32 A converted in-kernel (previous verified path) ----------
__global__ __launch_bounds__(256) void k_gemm(
        const float* __restrict__ x, const u16* __restrict__ bt,
        const float* __restrict__ bias, float* __restrict__ out) {
    __shared__ u16 As[128 * BKK] __attribute__((aligned(16)));
    __shared__ u16 Bs[128 * BKK] __attribute__((aligned(16)));

    int bid = blockIdx.x;
    int xcd = bid & 7;
    int rest = bid >> 3;
    int n_t = rest % 5;
    int m_t = (rest / 5) * 8 + xcd;
    if (m_t >= 150) return;

    int tid = threadIdx.x;
    int wave = tid >> 6;
    int lane = tid & 63;
    int wr = wave >> 1, wc = wave & 1;
    int quad = lane >> 4;
    int l16 = lane & 15;

    f32x4 acc[4][4] = {};

    const float* a_base = x  + (size_t)m_t * 128 * DD;
    const u16*   b_base = bt + (size_t)n_t * 128 * DD;
    int s_row = lane >> 3;
    int s_c16 = lane & 7;
    int arow8 = tid >> 4;
    int acol4 = tid & 15;

    for (int k0 = 0; k0 < DD; k0 += BKK) {
#pragma unroll
        for (int q = 0; q < 4; ++q) {
            int rowblk = q * 32 + wave * 8;
            const u16* gb = b_base + (size_t)(rowblk + s_row) * DD + k0 + s_c16 * 8;
            __builtin_amdgcn_global_load_lds((const GLOBAL_AS unsigned int*)gb,
                                             (LDS_AS unsigned int*)(Bs + rowblk * BKK),
                                             16, 0, 0);
        }
#pragma unroll
        for (int it = 0; it < 8; ++it) {
            int row = it * 16 + arow8;
            float4 av = *(const float4*)(a_base + (size_t)row * DD + k0 + acol4 * 4);
            unsigned lo = __builtin_amdgcn_perm(__float_as_uint(av.y), __float_as_uint(av.x), 0x07060302u);
            unsigned hi = __builtin_amdgcn_perm(__float_as_uint(av.w), __float_as_uint(av.z), 0x07060302u);
            *(uint2*)(As + row * BKK + acol4 * 4) = make_uint2(lo, hi);
        }
        __syncthreads();
#pragma unroll
        for (int kk = 0; kk < BKK; kk += 32) {
            bf16x8 af[4], bfv[4];
#pragma unroll
            for (int f = 0; f < 4; ++f) {
                int m = wr * 64 + f * 16 + l16;
                af[f] = *(const bf16x8*)(As + m * BKK + kk + quad * 8);
                int n = wc * 64 + f * 16 + l16;
                bfv[f] = *(const bf16x8*)(Bs + n * BKK + kk + quad * 8);
            }
#pragma unroll
            for (int fi = 0; fi < 4; ++fi)
#pragma unroll
                for (int fj = 0; fj < 4; ++fj)
                    acc[fi][fj] = __builtin_amdgcn_mfma_f32_16x16x32_bf16(
                        af[fi], bfv[fj], acc[fi][fj], 0, 0, 0);
        }
        __syncthreads();
    }

#pragma unroll
    for (int fj = 0; fj < 4; ++fj) {
        int col = n_t * 128 + wc * 64 + fj * 16 + l16;
        if (col < NOUT) {
            float bia = bias[col];
#pragma unroll
            for (int fi = 0; fi < 4; ++fi) {
#pragma unroll
                for (int rg = 0; rg < 4; ++rg) {
                    int row = m_t * 128 + wr * 64 + fi * 16 + quad * 4 + rg;
                    out[(size_t)row * NOUT + col] = acc[fi][fj][rg] + bia;
                }
            }
        }
    }
}

extern "C" void kernel_launch(void* const* d_in, const int* in_sizes, int n_in,
                              void* d_out, int out_size, void* d_ws, size_t ws_size,
                              hipStream_t stream) {
    // ---- input binding by element counts (proven equivalent to dict order) ----
    const void* P[12] = {};
    int sv[3] = {-1, -1, -1}; int nsv = 0;
    int sc[2] = {-1, -1};     int nsc = 0;
    for (int i = 0; i < n_in; ++i) {
        switch (in_sizes[i]) {
            case 19660800: P[0]  = d_in[i]; break;
            case 65536:    if (nsv < 3) sv[nsv++] = i; break;
            case 1048576:  P[4]  = d_in[i]; break;
            case 1024:     P[5]  = d_in[i]; break;
            case 3072:     P[6]  = d_in[i]; break;
            case 1:        if (nsc < 2) sc[nsc++] = i; break;
            case 2048:     P[8]  = d_in[i]; break;
            case 618496:   P[10] = d_in[i]; break;
            case 604:      P[11] = d_in[i]; break;
            default: break;
        }
    }
    bool alpha = (n_in == 12 && in_sizes[0] == 618496);
    if (alpha) {
        P[2] = d_in[sv[0]]; P[3] = d_in[sv[1]]; P[1] = d_in[sv[2]];
        P[9] = d_in[sc[0]]; P[7] = d_in[sc[1]];
    } else {
        P[1] = d_in[sv[0]]; P[2] = d_in[sv[1]]; P[3] = d_in[sv[2]];
        P[7] = d_in[sc[0]]; P[9] = d_in[sc[1]];
    }
    const float* x        = (const float*)P[0];
    const float* subject  = (const float*)P[1];
    const float* obj      = (const float*)P[2];
    const float* relation = (const float*)P[3];
    const float* W_theta  = (const float*)P[4];
    const float* b_theta  = (const float*)P[5];
    const float* W_pair   = (const float*)P[6];
    const float* b_pair   = (const float*)P[7];
    const float* W_cls    = (const float*)P[8];
    const float* b_cls    = (const float*)P[9];
    const float* W_bbox   = (const float*)P[10];
    const float* b_bbox   = (const float*)P[11];
    float* out = (float*)d_out;

    // ws layout
    char* ws = (char*)d_ws;
    float* v    = (float*)(ws + 0);         // 1024 f32
    float* relt = (float*)(ws + 4096);      // 64 f32
    float* subc = (float*)(ws + 4352);      // 64 f32
    float* objc = (float*)(ws + 4608);      // 64 f32
    float* colv = (float*)(ws + 4864);      // 19200 f32
    float* rowp = (float*)(ws + 81664);     // 19200 f32
    float* sarr = (float*)(ws + 158464);    // 19200 f32
    float* oarr = (float*)(ws + 235264);    // 19200 f32 (end 312,064)
    u16*   Bt   = (u16*)(ws + 312064);      // 640*1024 bf16 = 1,310,720 B (end 1,622,784)
    u16*   Xb   = (u16*)(ws + 1622784);     // 19200*1024 bf16 = 39,321,600 B (end 40,944,384)

    const size_t WS_NEED_BF16 = 40944384;
    bool big_ws = (ws_size >= WS_NEED_BF16);

    k_transpose<<<dim3(32, 20), dim3(32, 8), 0, stream>>>(W_bbox, Bt);
    k_vtheta<<<256, 256, 0, stream>>>(W_theta, W_pair, v);
    k_scalars<<<64, 256, 0, stream>>>(relation, subject, obj, b_theta, W_pair, b_pair,
                                      W_cls, b_cls, v, relt, subc, objc);
    if (big_ws) {
        k_rows<1><<<4800, 256, 0, stream>>>(x, W_pair, W_cls, relt, subc, objc,
                                            colv, rowp, sarr, oarr, out, Xb);
    } else {
        k_rows<0><<<4800, 256, 0, stream>>>(x, W_pair, W_cls, relt, subc, objc,
                                            colv, rowp, sarr, oarr, out, nullptr);
    }
    k_pair<<<1920, 192, 0, stream>>>(rowp, colv, sarr, oarr, out + OFF_PAIR);
    if (big_ws) {
        k_gemm_bf<<<760, 256, 0, stream>>>(Xb, Bt, b_bbox, out + OFF_BBOX);
    } else {
        k_gemm<<<760, 256, 0, stream>>>(x, Bt, b_bbox, out + OFF_BBOX);
    }
}

// Round 3
// 209.411 us; speedup vs baseline: 1.1168x; 1.0730x over previous
//
#include <hip/hip_runtime.h>

// ---------- constants ----------
#define PP    300
#define DD    1024
#define NOUT  604          // (150+1)*4
#define NROWS 19200        // 64*300
// output element offsets (fp32 elements)
#define OFF_PAIR  76800
#define OFF_BBOX  5836800  // 76800 + 64*300*300

typedef unsigned short u16;
typedef __attribute__((ext_vector_type(8))) short bf16x8;
typedef __attribute__((ext_vector_type(4))) float f32x4;

#define GLOBAL_AS __attribute__((address_space(1)))
#define LDS_AS    __attribute__((address_space(3)))

__device__ inline u16 f2bf(float f) {
    unsigned u = __float_as_uint(f);
    return (u16)((u + 0x7fffu + ((u >> 16) & 1u)) >> 16);
}
__device__ inline float dot4(float4 a, float4 b) {
    return fmaf(a.x, b.x, fmaf(a.y, b.y, fmaf(a.z, b.z, a.w * b.w)));
}
__device__ inline float sigmoidf(float z) { return 1.f / (1.f + __expf(-z)); }

// ---------- kernel 1: prep = transpose W_bbox (blocks 0..639) + vtheta (blocks 640..895) ----------
__global__ __launch_bounds__(256) void k_prep(const float* __restrict__ Wbbox, u16* __restrict__ Bt,
                                              const float* __restrict__ Wt, const float* __restrict__ Wpair,
                                              float* __restrict__ v) {
    __shared__ float tile[32][33];
    int blk = blockIdx.x;
    int tid = threadIdx.x;
    if (blk < 640) {
        // transpose+pad W_bbox (1024x604 f32) -> Bt (640x1024 bf16)
        int k0 = (blk & 31) * 32;
        int n0 = (blk >> 5) * 32;
        int tx = tid & 31;          // 0..31
        int ty = tid >> 5;          // 0..7
#pragma unroll
        for (int i = 0; i < 4; ++i) {
            int k = k0 + ty + i * 8;
            int n = n0 + tx;
            tile[ty + i * 8][tx] = (n < NOUT) ? Wbbox[(size_t)k * NOUT + n] : 0.f;
        }
        __syncthreads();
#pragma unroll
        for (int i = 0; i < 4; ++i) {
            int n = n0 + ty + i * 8;
            int k = k0 + tx;
            Bt[(size_t)n * DD + k] = f2bf(tile[tx][ty + i * 8]);
        }
    } else {
        // v = W_theta @ Wc  (Wc = W_pair[2048:3072])
        int wave = tid >> 6, lane = tid & 63;
        int k = (blk - 640) * 4 + wave;           // 0..1023
        const float4* row = (const float4*)(Wt + (size_t)k * DD);
        const float4* wc  = (const float4*)(Wpair + 2 * DD);
        float s = 0.f;
#pragma unroll
        for (int i = 0; i < 4; ++i) s += dot4(row[i * 64 + lane], wc[i * 64 + lane]);
#pragma unroll
        for (int off = 32; off; off >>= 1) s += __shfl_down(s, off, 64);
        if (lane == 0) v[k] = s;
    }
}

// ---------- kernel 2: per-batch scalars ----------
__global__ void k_scalars(const float* __restrict__ relation, const float* __restrict__ subject,
                          const float* __restrict__ obj, const float* __restrict__ btheta,
                          const float* __restrict__ Wpair, const float* __restrict__ bpair,
                          const float* __restrict__ Wcls, const float* __restrict__ bcls,
                          const float* __restrict__ v,
                          float* __restrict__ relt, float* __restrict__ subc,
                          float* __restrict__ objc) {
    __shared__ float red[4];
    int wave = threadIdx.x >> 6, lane = threadIdx.x & 63;
    int b = blockIdx.x;
    const float4* aa;
    const float4* bb;
    if (wave == 0)      { aa = (const float4*)(relation + (size_t)b * DD); bb = (const float4*)v; }
    else if (wave == 1) { aa = (const float4*)(subject + (size_t)b * DD);  bb = (const float4*)(Wcls + DD); }
    else if (wave == 2) { aa = (const float4*)(obj + (size_t)b * DD);      bb = (const float4*)(Wcls + DD); }
    else                { aa = (const float4*)btheta;                      bb = (const float4*)(Wpair + 2 * DD); }
    float s = 0.f;
#pragma unroll
    for (int i = 0; i < 4; ++i) s += dot4(aa[i * 64 + lane], bb[i * 64 + lane]);
#pragma unroll
    for (int off = 32; off; off >>= 1) s += __shfl_down(s, off, 64);
    if (lane == 0) red[wave] = s;
    __syncthreads();
    if (threadIdx.x == 0) {
        relt[b] = red[0] + red[3] + bpair[0];
        subc[b] = red[1] + bcls[0];
        objc[b] = red[2] + bcls[0];
    }
}

// ---------- kernel 3: per-row dots + fp32 x_subj/x_obj outputs (+ optional bf16 x copy) ----------
template<int WB>
__global__ __launch_bounds__(256) void k_rows(
        const float* __restrict__ x, const float* __restrict__ Wpair,
        const float* __restrict__ Wcls,
        const float* __restrict__ relt, const float* __restrict__ subc,
        const float* __restrict__ objc,
        float* __restrict__ colv, float* __restrict__ rowp,
        float* __restrict__ sarr, float* __restrict__ oarr,
        float* __restrict__ out, u16* __restrict__ xb) {
    int wave = threadIdx.x >> 6, lane = threadIdx.x & 63;
    int r = blockIdx.x * 4 + wave;                // 0..19199
    const float4* xr = (const float4*)(x + (size_t)r * DD);
    const float4* wa = (const float4*)(Wpair);
    const float4* wb = (const float4*)(Wpair + DD);
    const float4* w1 = (const float4*)(Wcls);
    float ca = 0.f, cb = 0.f, cw = 0.f;
#pragma unroll
    for (int i = 0; i < 4; ++i) {
        int idx = i * 64 + lane;
        float4 xv = xr[idx];
        ca += dot4(xv, wa[idx]);
        cb += dot4(xv, wb[idx]);
        cw += dot4(xv, w1[idx]);
        if (WB) {
            // truncate fp32 -> bf16 (identical numerics to the fallback GEMM's in-kernel perm)
            unsigned lo = __builtin_amdgcn_perm(__float_as_uint(xv.y), __float_as_uint(xv.x), 0x07060302u);
            unsigned hi = __builtin_amdgcn_perm(__float_as_uint(xv.w), __float_as_uint(xv.z), 0x07060302u);
            *(uint2*)(xb + (size_t)r * DD + idx * 4) = make_uint2(lo, hi);
        }
    }
#pragma unroll
    for (int off = 32; off; off >>= 1) {
        ca += __shfl_down(ca, off, 64);
        cb += __shfl_down(cb, off, 64);
        cw += __shfl_down(cw, off, 64);
    }
    if (lane == 0) {
        int b = r / 300;
        float s = sigmoidf(cw + subc[b]);
        float o = sigmoidf(cw + objc[b]);
        colv[r] = ca;
        rowp[r] = cb + relt[b];
        sarr[r] = s;
        oarr[r] = o;
        ((float2*)out)[r]         = make_float2(1.f - s, s);   // x_subj pair (fp32)
        ((float2*)out)[NROWS + r] = make_float2(1.f - o, o);   // x_obj pair (fp32)
    }
}

// ---------- kernel 4: fused bbox-GEMM (blocks 0..759) + pair_score (blocks 760..2679) ----------
// GEMM: bf16 A from workspace, XOR-swizzled LDS (verified R2, conflicts=0), now with
// double-buffered LDS and stage-BEFORE-compute so the single __syncthreads/K-step drains
// loads whose latency was hidden under the current tile's ds_read+MFMA (T3 minimum-2-phase,
// m230/m248 pattern). Manual 2x unroll keeps buffer indices compile-time.
#define BKK 64
#define NSTEP 16           // DD/BKK

#define STAGE_TILE(buf, k0)                                                                  \
    _Pragma("unroll")                                                                        \
    for (int q = 0; q < 4; ++q) {                                                            \
        int rowblk = q * 32 + wave * 8;                                                      \
        const u16* ga = a_base + (size_t)(rowblk + s_row) * DD + (k0) + s_c16 * 8;           \
        __builtin_amdgcn_global_load_lds((const GLOBAL_AS unsigned int*)ga,                  \
                                         (LDS_AS unsigned int*)(As[buf] + rowblk * BKK),     \
                                         16, 0, 0);                                          \
        const u16* gb = b_base + (size_t)(rowblk + s_row) * DD + (k0) + s_c16 * 8;           \
        __builtin_amdgcn_global_load_lds((const GLOBAL_AS unsigned int*)gb,                  \
                                         (LDS_AS unsigned int*)(Bs[buf] + rowblk * BKK),     \
                                         16, 0, 0);                                          \
    }

#define COMPUTE_TILE(buf)                                                                    \
    _Pragma("unroll")                                                                        \
    for (int kk = 0; kk < BKK; kk += 32) {                                                   \
        bf16x8 af[4], bfv[4];                                                                \
        int cx = (((kk >> 3) + quad) ^ (l16 & 7)) * 8;                                       \
        _Pragma("unroll")                                                                    \
        for (int f = 0; f < 4; ++f) {                                                        \
            int m = wr * 64 + f * 16 + l16;                                                  \
            af[f] = *(const bf16x8*)(As[buf] + m * BKK + cx);                                \
            int n = wc * 64 + f * 16 + l16;                                                  \
            bfv[f] = *(const bf16x8*)(Bs[buf] + n * BKK + cx);                               \
        }                                                                                    \
        _Pragma("unroll")                                                                    \
        for (int fi = 0; fi < 4; ++fi)                                                       \
            _Pragma("unroll")                                                                \
            for (int fj = 0; fj < 4; ++fj)                                                   \
                acc[fi][fj] = __builtin_amdgcn_mfma_f32_16x16x32_bf16(                       \
                    af[fi], bfv[fj], acc[fi][fj], 0, 0, 0);                                  \
    }

__global__ __launch_bounds__(256) void k_fused(
        const u16* __restrict__ xb, const u16* __restrict__ bt,
        const float* __restrict__ bias, float* __restrict__ outb,
        const float* __restrict__ rowp, const float* __restrict__ colv,
        const float* __restrict__ sarr, const float* __restrict__ oarr,
        float* __restrict__ pout) {
    __shared__ u16 As[2][128 * BKK] __attribute__((aligned(16)));
    __shared__ u16 Bs[2][128 * BKK] __attribute__((aligned(16)));

    int gbid = blockIdx.x;
    if (gbid < 760) {
        // ---------------- GEMM path ----------------
        int xcd = gbid & 7;
        int rest = gbid >> 3;
        int n_t = rest % 5;
        int m_t = (rest / 5) * 8 + xcd;
        if (m_t >= 150) return;

        int tid = threadIdx.x;
        int wave = tid >> 6;
        int lane = tid & 63;
        int wr = wave >> 1, wc = wave & 1;
        int quad = lane >> 4;
        int l16 = lane & 15;

        f32x4 acc[4][4] = {};

        const u16* a_base = xb + (size_t)m_t * 128 * DD;
        const u16* b_base = bt + (size_t)n_t * 128 * DD;
        int s_row = lane >> 3;              // 0..7 (row within 8-row staging block)
        int s_c16 = (lane & 7) ^ s_row;     // pre-swizzled source 16B-chunk (XOR involution)

        STAGE_TILE(0, 0)
        __syncthreads();

#pragma unroll 1
        for (int t = 0; t < NSTEP; t += 2) {
            // even step: stage t+1 into buf1, compute buf0
            STAGE_TILE(1, (t + 1) * BKK)
            COMPUTE_TILE(0)
            __syncthreads();                 // drains buf1 loads (latency hidden by compute)
            // odd step: stage t+2 into buf0 (if any), compute buf1
            if (t + 2 < NSTEP) { STAGE_TILE(0, (t + 2) * BKK) }
            COMPUTE_TILE(1)
            __syncthreads();
        }

        // epilogue: add bias, mask col<604, store fp32
#pragma unroll
        for (int fj = 0; fj < 4; ++fj) {
            int col = n_t * 128 + wc * 64 + fj * 16 + l16;
            if (col < NOUT) {
                float bia = bias[col];
#pragma unroll
                for (int fi = 0; fi < 4; ++fi) {
#pragma unroll
                    for (int rg = 0; rg < 4; ++rg) {
                        int row = m_t * 128 + wr * 64 + fi * 16 + quad * 4 + rg;
                        outb[(size_t)row * NOUT + col] = acc[fi][fj][rg] + bia;
                    }
                }
            }
        }
    } else {
        // ---------------- pair_score path (independent work; hides under GEMM) ----------------
        float* cb_s = (float*)As;            // alias LDS (disjoint block paths)
        float* ob_s = ((float*)As) + 300;
        int blk = gbid - 760;                // 0..1919
        int b = blk / 30;
        int chunk = blk - b * 30;            // 0..29
        int r0 = b * 300 + chunk * 10;
        int tid = threadIdx.x;
        for (int j = tid; j < 300; j += 256) {
            cb_s[j] = colv[b * 300 + j];
            ob_s[j] = oarr[b * 300 + j];
        }
        __syncthreads();
        if (tid < 150) {
            float c0 = cb_s[2 * tid], c1 = cb_s[2 * tid + 1];
            float o0 = ob_s[2 * tid], o1 = ob_s[2 * tid + 1];
#pragma unroll
            for (int rr = 0; rr < 10; ++rr) {
                int r = r0 + rr;
                float rp = rowp[r];
                float ss = sarr[r];
                float p0 = sigmoidf(rp + c0) * o0 * ss;
                float p1 = sigmoidf(rp + c1) * o1 * ss;
                ((float2*)(pout + (size_t)r * 300))[tid] = make_float2(p0, p1);
            }
        }
    }
}

// ---------- fallback kernels (small workspace): previous verified path ----------
__global__ __launch_bounds__(192) void k_pair_sa(
        const float* __restrict__ rowp, const float* __restrict__ colv,
        const float* __restrict__ sarr, const float* __restrict__ oarr,
        float* __restrict__ pout) {
    __shared__ float cb_s[300];
    __shared__ float ob_s[300];
    int blk = blockIdx.x;               // 0..1919
    int b = blk / 30;
    int chunk = blk - b * 30;           // 0..29
    int r0 = b * 300 + chunk * 10;
    int tid = threadIdx.x;
    for (int j = tid; j < 300; j += 192) {
        cb_s[j] = colv[b * 300 + j];
        ob_s[j] = oarr[b * 300 + j];
    }
    __syncthreads();
    if (tid < 150) {
        float c0 = cb_s[2 * tid], c1 = cb_s[2 * tid + 1];
        float o0 = ob_s[2 * tid], o1 = ob_s[2 * tid + 1];
#pragma unroll
        for (int rr = 0; rr < 10; ++rr) {
            int r = r0 + rr;
            float rp = rowp[r];
            float ss = sarr[r];
            float p0 = sigmoidf(rp + c0) * o0 * ss;
            float p1 = sigmoidf(rp + c1) * o1 * ss;
            ((float2*)(pout + (size_t)r * 300))[tid] = make_float2(p0, p1);
        }
    }
}

__global__ __launch_bounds__(256) void k_gemm(
        const float* __restrict__ x, const u16* __restrict__ bt,
        const float* __restrict__ bias, float* __restrict__ out) {
    __shared__ u16 As[128 * BKK] __attribute__((aligned(16)));
    __shared__ u16 Bs[128 * BKK] __attribute__((aligned(16)));

    int bid = blockIdx.x;
    int xcd = bid & 7;
    int rest = bid >> 3;
    int n_t = rest % 5;
    int m_t = (rest / 5) * 8 + xcd;
    if (m_t >= 150) return;

    int tid = threadIdx.x;
    int wave = tid >> 6;
    int lane = tid & 63;
    int wr = wave >> 1, wc = wave & 1;
    int quad = lane >> 4;
    int l16 = lane & 15;

    f32x4 acc[4][4] = {};

    const float* a_base = x  + (size_t)m_t * 128 * DD;
    const u16*   b_base = bt + (size_t)n_t * 128 * DD;
    int s_row = lane >> 3;
    int s_c16 = lane & 7;
    int arow8 = tid >> 4;
    int acol4 = tid & 15;

    for (int k0 = 0; k0 < DD; k0 += BKK) {
#pragma unroll
        for (int q = 0; q < 4; ++q) {
            int rowblk = q * 32 + wave * 8;
            const u16* gb = b_base + (size_t)(rowblk + s_row) * DD + k0 + s_c16 * 8;
            __builtin_amdgcn_global_load_lds((const GLOBAL_AS unsigned int*)gb,
                                             (LDS_AS unsigned int*)(Bs + rowblk * BKK),
                                             16, 0, 0);
        }
#pragma unroll
        for (int it = 0; it < 8; ++it) {
            int row = it * 16 + arow8;
            float4 av = *(const float4*)(a_base + (size_t)row * DD + k0 + acol4 * 4);
            unsigned lo = __builtin_amdgcn_perm(__float_as_uint(av.y), __float_as_uint(av.x), 0x07060302u);
            unsigned hi = __builtin_amdgcn_perm(__float_as_uint(av.w), __float_as_uint(av.z), 0x07060302u);
            *(uint2*)(As + row * BKK + acol4 * 4) = make_uint2(lo, hi);
        }
        __syncthreads();
#pragma unroll
        for (int kk = 0; kk < BKK; kk += 32) {
            bf16x8 af[4], bfv[4];
#pragma unroll
            for (int f = 0; f < 4; ++f) {
                int m = wr * 64 + f * 16 + l16;
                af[f] = *(const bf16x8*)(As + m * BKK + kk + quad * 8);
                int n = wc * 64 + f * 16 + l16;
                bfv[f] = *(const bf16x8*)(Bs + n * BKK + kk + quad * 8);
            }
#pragma unroll
            for (int fi = 0; fi < 4; ++fi)
#pragma unroll
                for (int fj = 0; fj < 4; ++fj)
                    acc[fi][fj] = __builtin_amdgcn_mfma_f32_16x16x32_bf16(
                        af[fi], bfv[fj], acc[fi][fj], 0, 0, 0);
        }
        __syncthreads();
    }

#pragma unroll
    for (int fj = 0; fj < 4; ++fj) {
        int col = n_t * 128 + wc * 64 + fj * 16 + l16;
        if (col < NOUT) {
            float bia = bias[col];
#pragma unroll
            for (int fi = 0; fi < 4; ++fi) {
#pragma unroll
                for (int rg = 0; rg < 4; ++rg) {
                    int row = m_t * 128 + wr * 64 + fi * 16 + quad * 4 + rg;
                    out[(size_t)row * NOUT + col] = acc[fi][fj][rg] + bia;
                }
            }
        }
    }
}

extern "C" void kernel_launch(void* const* d_in, const int* in_sizes, int n_in,
                              void* d_out, int out_size, void* d_ws, size_t ws_size,
                              hipStream_t stream) {
    // ---- input binding by element counts (proven equivalent to dict order) ----
    const void* P[12] = {};
    int sv[3] = {-1, -1, -1}; int nsv = 0;
    int sc[2] = {-1, -1};     int nsc = 0;
    for (int i = 0; i < n_in; ++i) {
        switch (in_sizes[i]) {
            case 19660800: P[0]  = d_in[i]; break;
            case 65536:    if (nsv < 3) sv[nsv++] = i; break;
            case 1048576:  P[4]  = d_in[i]; break;
            case 1024:     P[5]  = d_in[i]; break;
            case 3072:     P[6]  = d_in[i]; break;
            case 1:        if (nsc < 2) sc[nsc++] = i; break;
            case 2048:     P[8]  = d_in[i]; break;
            case 618496:   P[10] = d_in[i]; break;
            case 604:      P[11] = d_in[i]; break;
            default: break;
        }
    }
    bool alpha = (n_in == 12 && in_sizes[0] == 618496);
    if (alpha) {
        P[2] = d_in[sv[0]]; P[3] = d_in[sv[1]]; P[1] = d_in[sv[2]];
        P[9] = d_in[sc[0]]; P[7] = d_in[sc[1]];
    } else {
        P[1] = d_in[sv[0]]; P[2] = d_in[sv[1]]; P[3] = d_in[sv[2]];
        P[7] = d_in[sc[0]]; P[9] = d_in[sc[1]];
    }
    const float* x        = (const float*)P[0];
    const float* subject  = (const float*)P[1];
    const float* obj      = (const float*)P[2];
    const float* relation = (const float*)P[3];
    const float* W_theta  = (const float*)P[4];
    const float* b_theta  = (const float*)P[5];
    const float* W_pair   = (const float*)P[6];
    const float* b_pair   = (const float*)P[7];
    const float* W_cls    = (const float*)P[8];
    const float* b_cls    = (const float*)P[9];
    const float* W_bbox   = (const float*)P[10];
    const float* b_bbox   = (const float*)P[11];
    float* out = (float*)d_out;

    // ws layout
    char* ws = (char*)d_ws;
    float* v    = (float*)(ws + 0);         // 1024 f32
    float* relt = (float*)(ws + 4096);      // 64 f32
    float* subc = (float*)(ws + 4352);      // 64 f32
    float* objc = (float*)(ws + 4608);      // 64 f32
    float* colv = (float*)(ws + 4864);      // 19200 f32
    float* rowp = (float*)(ws + 81664);     // 19200 f32
    float* sarr = (float*)(ws + 158464);    // 19200 f32
    float* oarr = (float*)(ws + 235264);    // 19200 f32 (end 312,064)
    u16*   Bt   = (u16*)(ws + 312064);      // 640*1024 bf16 = 1,310,720 B (end 1,622,784)
    u16*   Xb   = (u16*)(ws + 1622784);     // 19200*1024 bf16 = 39,321,600 B (end 40,944,384)

    const size_t WS_NEED_BF16 = 40944384;
    bool big_ws = (ws_size >= WS_NEED_BF16);

    k_prep<<<896, 256, 0, stream>>>(W_bbox, Bt, W_theta, W_pair, v);
    k_scalars<<<64, 256, 0, stream>>>(relation, subject, obj, b_theta, W_pair, b_pair,
                                      W_cls, b_cls, v, relt, subc, objc);
    if (big_ws) {
        k_rows<1><<<4800, 256, 0, stream>>>(x, W_pair, W_cls, relt, subc, objc,
                                            colv, rowp, sarr, oarr, out, Xb);
        k_fused<<<2680, 256, 0, stream>>>(Xb, Bt, b_bbox, out + OFF_BBOX,
                                          rowp, colv, sarr, oarr, out + OFF_PAIR);
    } else {
        k_rows<0><<<4800, 256, 0, stream>>>(x, W_pair, W_cls, relt, subc, objc,
                                            colv, rowp, sarr, oarr, out, nullptr);
        k_pair_sa<<<1920, 192, 0, stream>>>(rowp, colv, sarr, oarr, out + OFF_PAIR);
        k_gemm<<<760, 256, 0, stream>>>(x, Bt, b_bbox, out + OFF_BBOX);
    }
}

// Round 4
// 206.631 us; speedup vs baseline: 1.1318x; 1.0135x over previous
//
#include <hip/hip_runtime.h>

// ---------- constants ----------
#define PP    300
#define DD    1024
#define NOUT  604          // (150+1)*4
#define NROWS 19200        // 64*300
// output element offsets (fp32 elements)
#define OFF_PAIR  76800
#define OFF_BBOX  5836800  // 76800 + 64*300*300

typedef unsigned short u16;
typedef __attribute__((ext_vector_type(8))) short bf16x8;
typedef __attribute__((ext_vector_type(4))) float f32x4;

#define GLOBAL_AS __attribute__((address_space(1)))
#define LDS_AS    __attribute__((address_space(3)))

__device__ inline u16 f2bf(float f) {
    unsigned u = __float_as_uint(f);
    return (u16)((u + 0x7fffu + ((u >> 16) & 1u)) >> 16);
}
__device__ inline float dot4(float4 a, float4 b) {
    return fmaf(a.x, b.x, fmaf(a.y, b.y, fmaf(a.z, b.z, a.w * b.w)));
}
__device__ inline float sigmoidf(float z) { return 1.f / (1.f + __expf(-z)); }

// ---------- kernel 1: prep = transpose W_bbox (blocks 0..639) + vtheta (blocks 640..895) ----------
__global__ __launch_bounds__(256) void k_prep(const float* __restrict__ Wbbox, u16* __restrict__ Bt,
                                              const float* __restrict__ Wt, const float* __restrict__ Wpair,
                                              float* __restrict__ v) {
    __shared__ float tile[32][33];
    int blk = blockIdx.x;
    int tid = threadIdx.x;
    if (blk < 640) {
        // transpose+pad W_bbox (1024x604 f32) -> Bt (640x1024 bf16)
        int k0 = (blk & 31) * 32;
        int n0 = (blk >> 5) * 32;
        int tx = tid & 31;          // 0..31
        int ty = tid >> 5;          // 0..7
#pragma unroll
        for (int i = 0; i < 4; ++i) {
            int k = k0 + ty + i * 8;
            int n = n0 + tx;
            tile[ty + i * 8][tx] = (n < NOUT) ? Wbbox[(size_t)k * NOUT + n] : 0.f;
        }
        __syncthreads();
#pragma unroll
        for (int i = 0; i < 4; ++i) {
            int n = n0 + ty + i * 8;
            int k = k0 + tx;
            Bt[(size_t)n * DD + k] = f2bf(tile[tx][ty + i * 8]);
        }
    } else {
        // v = W_theta @ Wc  (Wc = W_pair[2048:3072])
        int wave = tid >> 6, lane = tid & 63;
        int k = (blk - 640) * 4 + wave;           // 0..1023
        const float4* row = (const float4*)(Wt + (size_t)k * DD);
        const float4* wc  = (const float4*)(Wpair + 2 * DD);
        float s = 0.f;
#pragma unroll
        for (int i = 0; i < 4; ++i) s += dot4(row[i * 64 + lane], wc[i * 64 + lane]);
#pragma unroll
        for (int off = 32; off; off >>= 1) s += __shfl_down(s, off, 64);
        if (lane == 0) v[k] = s;
    }
}

// ---------- kernel 2: per-batch scalars ----------
__global__ void k_scalars(const float* __restrict__ relation, const float* __restrict__ subject,
                          const float* __restrict__ obj, const float* __restrict__ btheta,
                          const float* __restrict__ Wpair, const float* __restrict__ bpair,
                          const float* __restrict__ Wcls, const float* __restrict__ bcls,
                          const float* __restrict__ v,
                          float* __restrict__ relt, float* __restrict__ subc,
                          float* __restrict__ objc) {
    __shared__ float red[4];
    int wave = threadIdx.x >> 6, lane = threadIdx.x & 63;
    int b = blockIdx.x;
    const float4* aa;
    const float4* bb;
    if (wave == 0)      { aa = (const float4*)(relation + (size_t)b * DD); bb = (const float4*)v; }
    else if (wave == 1) { aa = (const float4*)(subject + (size_t)b * DD);  bb = (const float4*)(Wcls + DD); }
    else if (wave == 2) { aa = (const float4*)(obj + (size_t)b * DD);      bb = (const float4*)(Wcls + DD); }
    else                { aa = (const float4*)btheta;                      bb = (const float4*)(Wpair + 2 * DD); }
    float s = 0.f;
#pragma unroll
    for (int i = 0; i < 4; ++i) s += dot4(aa[i * 64 + lane], bb[i * 64 + lane]);
#pragma unroll
    for (int off = 32; off; off >>= 1) s += __shfl_down(s, off, 64);
    if (lane == 0) red[wave] = s;
    __syncthreads();
    if (threadIdx.x == 0) {
        relt[b] = red[0] + red[3] + bpair[0];
        subc[b] = red[1] + bcls[0];
        objc[b] = red[2] + bcls[0];
    }
}

// ---------- kernel 3: per-row dots + fp32 x_subj/x_obj outputs (+ optional bf16 x copy) ----------
template<int WB>
__global__ __launch_bounds__(256) void k_rows(
        const float* __restrict__ x, const float* __restrict__ Wpair,
        const float* __restrict__ Wcls,
        const float* __restrict__ relt, const float* __restrict__ subc,
        const float* __restrict__ objc,
        float* __restrict__ colv, float* __restrict__ rowp,
        float* __restrict__ sarr, float* __restrict__ oarr,
        float* __restrict__ out, u16* __restrict__ xb) {
    int wave = threadIdx.x >> 6, lane = threadIdx.x & 63;
    int r = blockIdx.x * 4 + wave;                // 0..19199
    const float4* xr = (const float4*)(x + (size_t)r * DD);
    const float4* wa = (const float4*)(Wpair);
    const float4* wb = (const float4*)(Wpair + DD);
    const float4* w1 = (const float4*)(Wcls);
    float ca = 0.f, cb = 0.f, cw = 0.f;
#pragma unroll
    for (int i = 0; i < 4; ++i) {
        int idx = i * 64 + lane;
        float4 xv = xr[idx];
        ca += dot4(xv, wa[idx]);
        cb += dot4(xv, wb[idx]);
        cw += dot4(xv, w1[idx]);
        if (WB) {
            // truncate fp32 -> bf16 (identical numerics to the fallback GEMM's in-kernel perm)
            unsigned lo = __builtin_amdgcn_perm(__float_as_uint(xv.y), __float_as_uint(xv.x), 0x07060302u);
            unsigned hi = __builtin_amdgcn_perm(__float_as_uint(xv.w), __float_as_uint(xv.z), 0x07060302u);
            *(uint2*)(xb + (size_t)r * DD + idx * 4) = make_uint2(lo, hi);
        }
    }
#pragma unroll
    for (int off = 32; off; off >>= 1) {
        ca += __shfl_down(ca, off, 64);
        cb += __shfl_down(cb, off, 64);
        cw += __shfl_down(cw, off, 64);
    }
    if (lane == 0) {
        int b = r / 300;
        float s = sigmoidf(cw + subc[b]);
        float o = sigmoidf(cw + objc[b]);
        colv[r] = ca;
        rowp[r] = cb + relt[b];
        sarr[r] = s;
        oarr[r] = o;
        ((float2*)out)[r]         = make_float2(1.f - s, s);   // x_subj pair (fp32)
        ((float2*)out)[NROWS + r] = make_float2(1.f - o, o);   // x_obj pair (fp32)
    }
}

// ---------- kernel 4: fused bbox-GEMM (blocks 0..759) + pair_score (blocks 760..2679) ----------
// GEMM: bf16 A, XOR-swizzled LDS (R2: conflicts=0), double-buffered (R3). NEW (R4):
// counted-vmcnt barriers (T4, m218 pattern). __syncthreads() lowers to a FULL
// "s_waitcnt vmcnt(0) lgkmcnt(0)" drain of the loads issued in the same half-step;
// replace with: own-wave s_waitcnt vmcnt(8) (previous tile's 8 loads landed; the 8
// just-issued stay in flight) + raw s_barrier (=> all waves' old loads landed).
// A second plain s_barrier protects the buffer about to be overwritten; each wave's
// ds_reads are complete before its MFMAs issue (compiler lgkmcnt), so no drain needed.
#define BKK 64
#define NSTEP 16           // DD/BKK

#define WAITCNT_VM(N) asm volatile("s_waitcnt vmcnt(" #N ")" ::: "memory")

#define STAGE_TILE(buf, k0)                                                                  \
    _Pragma("unroll")                                                                        \
    for (int q = 0; q < 4; ++q) {                                                            \
        int rowblk = q * 32 + wave * 8;                                                      \
        const u16* ga = a_base + (size_t)(rowblk + s_row) * DD + (k0) + s_c16 * 8;           \
        __builtin_amdgcn_global_load_lds((const GLOBAL_AS unsigned int*)ga,                  \
                                         (LDS_AS unsigned int*)(As[buf] + rowblk * BKK),     \
                                         16, 0, 0);                                          \
        const u16* gb = b_base + (size_t)(rowblk + s_row) * DD + (k0) + s_c16 * 8;           \
        __builtin_amdgcn_global_load_lds((const GLOBAL_AS unsigned int*)gb,                  \
                                         (LDS_AS unsigned int*)(Bs[buf] + rowblk * BKK),     \
                                         16, 0, 0);                                          \
    }

#define COMPUTE_TILE(buf)                                                                    \
    _Pragma("unroll")                                                                        \
    for (int kk = 0; kk < BKK; kk += 32) {                                                   \
        bf16x8 af[4], bfv[4];                                                                \
        int cx = (((kk >> 3) + quad) ^ (l16 & 7)) * 8;                                       \
        _Pragma("unroll")                                                                    \
        for (int f = 0; f < 4; ++f) {                                                        \
            int m = wr * 64 + f * 16 + l16;                                                  \
            af[f] = *(const bf16x8*)(As[buf] + m * BKK + cx);                                \
            int n = wc * 64 + f * 16 + l16;                                                  \
            bfv[f] = *(const bf16x8*)(Bs[buf] + n * BKK + cx);                               \
        }                                                                                    \
        _Pragma("unroll")                                                                    \
        for (int fi = 0; fi < 4; ++fi)                                                       \
            _Pragma("unroll")                                                                \
            for (int fj = 0; fj < 4; ++fj)                                                   \
                acc[fi][fj] = __builtin_amdgcn_mfma_f32_16x16x32_bf16(                       \
                    af[fi], bfv[fj], acc[fi][fj], 0, 0, 0);                                  \
    }

__global__ __launch_bounds__(256) void k_fused(
        const u16* __restrict__ xb, const u16* __restrict__ bt,
        const float* __restrict__ bias, float* __restrict__ outb,
        const float* __restrict__ rowp, const float* __restrict__ colv,
        const float* __restrict__ sarr, const float* __restrict__ oarr,
        float* __restrict__ pout) {
    __shared__ u16 As[2][128 * BKK] __attribute__((aligned(16)));
    __shared__ u16 Bs[2][128 * BKK] __attribute__((aligned(16)));

    int gbid = blockIdx.x;
    if (gbid < 760) {
        // ---------------- GEMM path ----------------
        int xcd = gbid & 7;
        int rest = gbid >> 3;
        int n_t = rest % 5;
        int m_t = (rest / 5) * 8 + xcd;
        if (m_t >= 150) return;

        int tid = threadIdx.x;
        int wave = tid >> 6;
        int lane = tid & 63;
        int wr = wave >> 1, wc = wave & 1;
        int quad = lane >> 4;
        int l16 = lane & 15;

        f32x4 acc[4][4] = {};

        const u16* a_base = xb + (size_t)m_t * 128 * DD;
        const u16* b_base = bt + (size_t)n_t * 128 * DD;
        int s_row = lane >> 3;              // 0..7 (row within 8-row staging block)
        int s_c16 = (lane & 7) ^ s_row;     // pre-swizzled source 16B-chunk (XOR involution)

        STAGE_TILE(0, 0)

#pragma unroll 1
        for (int t = 0; t < NSTEP; t += 2) {
            // even half-step: stage t+1 into buf1; wait own old-8 (buf0) only; compute buf0
            STAGE_TILE(1, (t + 1) * BKK)
            WAITCNT_VM(8);
            __builtin_amdgcn_s_barrier();
            COMPUTE_TILE(0)
            __builtin_amdgcn_s_barrier();    // all waves done reading buf0 (ds_reads complete pre-MFMA)
            // odd half-step: stage t+2 into buf0 (if any); wait buf1's loads; compute buf1
            if (t + 2 < NSTEP) {
                STAGE_TILE(0, (t + 2) * BKK)
                WAITCNT_VM(8);
            } else {
                WAITCNT_VM(0);
            }
            __builtin_amdgcn_s_barrier();
            COMPUTE_TILE(1)
            __builtin_amdgcn_s_barrier();
        }

        // epilogue: add bias, mask col<604, store fp32
#pragma unroll
        for (int fj = 0; fj < 4; ++fj) {
            int col = n_t * 128 + wc * 64 + fj * 16 + l16;
            if (col < NOUT) {
                float bia = bias[col];
#pragma unroll
                for (int fi = 0; fi < 4; ++fi) {
#pragma unroll
                    for (int rg = 0; rg < 4; ++rg) {
                        int row = m_t * 128 + wr * 64 + fi * 16 + quad * 4 + rg;
                        outb[(size_t)row * NOUT + col] = acc[fi][fj][rg] + bia;
                    }
                }
            }
        }
    } else {
        // ---------------- pair_score path (independent work; hides under GEMM) ----------------
        float* cb_s = (float*)As;            // alias LDS (disjoint block paths)
        float* ob_s = ((float*)As) + 300;
        int blk = gbid - 760;                // 0..1919
        int b = blk / 30;
        int chunk = blk - b * 30;            // 0..29
        int r0 = b * 300 + chunk * 10;
        int tid = threadIdx.x;
        for (int j = tid; j < 300; j += 256) {
            cb_s[j] = colv[b * 300 + j];
            ob_s[j] = oarr[b * 300 + j];
        }
        __syncthreads();
        if (tid < 150) {
            float c0 = cb_s[2 * tid], c1 = cb_s[2 * tid + 1];
            float o0 = ob_s[2 * tid], o1 = ob_s[2 * tid + 1];
#pragma unroll
            for (int rr = 0; rr < 10; ++rr) {
                int r = r0 + rr;
                float rp = rowp[r];
                float ss = sarr[r];
                float p0 = sigmoidf(rp + c0) * o0 * ss;
                float p1 = sigmoidf(rp + c1) * o1 * ss;
                ((float2*)(pout + (size_t)r * 300))[tid] = make_float2(p0, p1);
            }
        }
    }
}

// ---------- fallback kernels (small workspace): previous verified path ----------
__global__ __launch_bounds__(192) void k_pair_sa(
        const float* __restrict__ rowp, const float* __restrict__ colv,
        const float* __restrict__ sarr, const float* __restrict__ oarr,
        float* __restrict__ pout) {
    __shared__ float cb_s[300];
    __shared__ float ob_s[300];
    int blk = blockIdx.x;               // 0..1919
    int b = blk / 30;
    int chunk = blk - b * 30;           // 0..29
    int r0 = b * 300 + chunk * 10;
    int tid = threadIdx.x;
    for (int j = tid; j < 300; j += 192) {
        cb_s[j] = colv[b * 300 + j];
        ob_s[j] = oarr[b * 300 + j];
    }
    __syncthreads();
    if (tid < 150) {
        float c0 = cb_s[2 * tid], c1 = cb_s[2 * tid + 1];
        float o0 = ob_s[2 * tid], o1 = ob_s[2 * tid + 1];
#pragma unroll
        for (int rr = 0; rr < 10; ++rr) {
            int r = r0 + rr;
            float rp = rowp[r];
            float ss = sarr[r];
            float p0 = sigmoidf(rp + c0) * o0 * ss;
            float p1 = sigmoidf(rp + c1) * o1 * ss;
            ((float2*)(pout + (size_t)r * 300))[tid] = make_float2(p0, p1);
        }
    }
}

__global__ __launch_bounds__(256) void k_gemm(
        const float* __restrict__ x, const u16* __restrict__ bt,
        const float* __restrict__ bias, float* __restrict__ out) {
    __shared__ u16 As[128 * BKK] __attribute__((aligned(16)));
    __shared__ u16 Bs[128 * BKK] __attribute__((aligned(16)));

    int bid = blockIdx.x;
    int xcd = bid & 7;
    int rest = bid >> 3;
    int n_t = rest % 5;
    int m_t = (rest / 5) * 8 + xcd;
    if (m_t >= 150) return;

    int tid = threadIdx.x;
    int wave = tid >> 6;
    int lane = tid & 63;
    int wr = wave >> 1, wc = wave & 1;
    int quad = lane >> 4;
    int l16 = lane & 15;

    f32x4 acc[4][4] = {};

    const float* a_base = x  + (size_t)m_t * 128 * DD;
    const u16*   b_base = bt + (size_t)n_t * 128 * DD;
    int s_row = lane >> 3;
    int s_c16 = lane & 7;
    int arow8 = tid >> 4;
    int acol4 = tid & 15;

    for (int k0 = 0; k0 < DD; k0 += BKK) {
#pragma unroll
        for (int q = 0; q < 4; ++q) {
            int rowblk = q * 32 + wave * 8;
            const u16* gb = b_base + (size_t)(rowblk + s_row) * DD + k0 + s_c16 * 8;
            __builtin_amdgcn_global_load_lds((const GLOBAL_AS unsigned int*)gb,
                                             (LDS_AS unsigned int*)(Bs + rowblk * BKK),
                                             16, 0, 0);
        }
#pragma unroll
        for (int it = 0; it < 8; ++it) {
            int row = it * 16 + arow8;
            float4 av = *(const float4*)(a_base + (size_t)row * DD + k0 + acol4 * 4);
            unsigned lo = __builtin_amdgcn_perm(__float_as_uint(av.y), __float_as_uint(av.x), 0x07060302u);
            unsigned hi = __builtin_amdgcn_perm(__float_as_uint(av.w), __float_as_uint(av.z), 0x07060302u);
            *(uint2*)(As + row * BKK + acol4 * 4) = make_uint2(lo, hi);
        }
        __syncthreads();
#pragma unroll
        for (int kk = 0; kk < BKK; kk += 32) {
            bf16x8 af[4], bfv[4];
#pragma unroll
            for (int f = 0; f < 4; ++f) {
                int m = wr * 64 + f * 16 + l16;
                af[f] = *(const bf16x8*)(As + m * BKK + kk + quad * 8);
                int n = wc * 64 + f * 16 + l16;
                bfv[f] = *(const bf16x8*)(Bs + n * BKK + kk + quad * 8);
            }
#pragma unroll
            for (int fi = 0; fi < 4; ++fi)
#pragma unroll
                for (int fj = 0; fj < 4; ++fj)
                    acc[fi][fj] = __builtin_amdgcn_mfma_f32_16x16x32_bf16(
                        af[fi], bfv[fj], acc[fi][fj], 0, 0, 0);
        }
        __syncthreads();
    }

#pragma unroll
    for (int fj = 0; fj < 4; ++fj) {
        int col = n_t * 128 + wc * 64 + fj * 16 + l16;
        if (col < NOUT) {
            float bia = bias[col];
#pragma unroll
            for (int fi = 0; fi < 4; ++fi) {
#pragma unroll
                for (int rg = 0; rg < 4; ++rg) {
                    int row = m_t * 128 + wr * 64 + fi * 16 + quad * 4 + rg;
                    out[(size_t)row * NOUT + col] = acc[fi][fj][rg] + bia;
                }
            }
        }
    }
}

extern "C" void kernel_launch(void* const* d_in, const int* in_sizes, int n_in,
                              void* d_out, int out_size, void* d_ws, size_t ws_size,
                              hipStream_t stream) {
    // ---- input binding by element counts (proven equivalent to dict order) ----
    const void* P[12] = {};
    int sv[3] = {-1, -1, -1}; int nsv = 0;
    int sc[2] = {-1, -1};     int nsc = 0;
    for (int i = 0; i < n_in; ++i) {
        switch (in_sizes[i]) {
            case 19660800: P[0]  = d_in[i]; break;
            case 65536:    if (nsv < 3) sv[nsv++] = i; break;
            case 1048576:  P[4]  = d_in[i]; break;
            case 1024:     P[5]  = d_in[i]; break;
            case 3072:     P[6]  = d_in[i]; break;
            case 1:        if (nsc < 2) sc[nsc++] = i; break;
            case 2048:     P[8]  = d_in[i]; break;
            case 618496:   P[10] = d_in[i]; break;
            case 604:      P[11] = d_in[i]; break;
            default: break;
        }
    }
    bool alpha = (n_in == 12 && in_sizes[0] == 618496);
    if (alpha) {
        P[2] = d_in[sv[0]]; P[3] = d_in[sv[1]]; P[1] = d_in[sv[2]];
        P[9] = d_in[sc[0]]; P[7] = d_in[sc[1]];
    } else {
        P[1] = d_in[sv[0]]; P[2] = d_in[sv[1]]; P[3] = d_in[sv[2]];
        P[7] = d_in[sc[0]]; P[9] = d_in[sc[1]];
    }
    const float* x        = (const float*)P[0];
    const float* subject  = (const float*)P[1];
    const float* obj      = (const float*)P[2];
    const float* relation = (const float*)P[3];
    const float* W_theta  = (const float*)P[4];
    const float* b_theta  = (const float*)P[5];
    const float* W_pair   = (const float*)P[6];
    const float* b_pair   = (const float*)P[7];
    const float* W_cls    = (const float*)P[8];
    const float* b_cls    = (const float*)P[9];
    const float* W_bbox   = (const float*)P[10];
    const float* b_bbox   = (const float*)P[11];
    float* out = (float*)d_out;

    // ws layout
    char* ws = (char*)d_ws;
    float* v    = (float*)(ws + 0);         // 1024 f32
    float* relt = (float*)(ws + 4096);      // 64 f32
    float* subc = (float*)(ws + 4352);      // 64 f32
    float* objc = (float*)(ws + 4608);      // 64 f32
    float* colv = (float*)(ws + 4864);      // 19200 f32
    float* rowp = (float*)(ws + 81664);     // 19200 f32
    float* sarr = (float*)(ws + 158464);    // 19200 f32
    float* oarr = (float*)(ws + 235264);    // 19200 f32 (end 312,064)
    u16*   Bt   = (u16*)(ws + 312064);      // 640*1024 bf16 = 1,310,720 B (end 1,622,784)
    u16*   Xb   = (u16*)(ws + 1622784);     // 19200*1024 bf16 = 39,321,600 B (end 40,944,384)

    const size_t WS_NEED_BF16 = 40944384;
    bool big_ws = (ws_size >= WS_NEED_BF16);

    k_prep<<<896, 256, 0, stream>>>(W_bbox, Bt, W_theta, W_pair, v);
    k_scalars<<<64, 256, 0, stream>>>(relation, subject, obj, b_theta, W_pair, b_pair,
                                      W_cls, b_cls, v, relt, subc, objc);
    if (big_ws) {
        k_rows<1><<<4800, 256, 0, stream>>>(x, W_pair, W_cls, relt, subc, objc,
                                            colv, rowp, sarr, oarr, out, Xb);
        k_fused<<<2680, 256, 0, stream>>>(Xb, Bt, b_bbox, out + OFF_BBOX,
                                          rowp, colv, sarr, oarr, out + OFF_PAIR);
    } else {
        k_rows<0><<<4800, 256, 0, stream>>>(x, W_pair, W_cls, relt, subc, objc,
                                            colv, rowp, sarr, oarr, out, nullptr);
        k_pair_sa<<<1920, 192, 0, stream>>>(rowp, colv, sarr, oarr, out + OFF_PAIR);
        k_gemm<<<760, 256, 0, stream>>>(x, Bt, b_bbox, out + OFF_BBOX);
    }
}

// Round 6
// 204.666 us; speedup vs baseline: 1.1427x; 1.0096x over previous
//
#include <hip/hip_runtime.h>

// ---------- constants ----------
#define PP    300
#define DD    1024
#define NOUT  604          // (150+1)*4
#define NROWS 19200        // 64*300
// output element offsets (fp32 elements)
#define OFF_PAIR  76800
#define OFF_BBOX  5836800  // 76800 + 64*300*300

typedef unsigned short u16;
typedef __attribute__((ext_vector_type(8))) short bf16x8;
typedef __attribute__((ext_vector_type(4))) float f32x4;

#define GLOBAL_AS __attribute__((address_space(1)))
#define LDS_AS    __attribute__((address_space(3)))

__device__ inline u16 f2bf(float f) {
    unsigned u = __float_as_uint(f);
    return (u16)((u + 0x7fffu + ((u >> 16) & 1u)) >> 16);
}
__device__ inline float dot4(float4 a, float4 b) {
    return fmaf(a.x, b.x, fmaf(a.y, b.y, fmaf(a.z, b.z, a.w * b.w)));
}
__device__ inline float sigmoidf(float z) { return 1.f / (1.f + __expf(-z)); }

// ---------- kernel: v = W_theta @ Wc  (Wc = W_pair[2048:3072]) ----------
__global__ void k_vtheta(const float* __restrict__ Wt, const float* __restrict__ Wpair,
                         float* __restrict__ v) {
    int wave = threadIdx.x >> 6, lane = threadIdx.x & 63;
    int k = blockIdx.x * 4 + wave;                // 0..1023
    const float4* row = (const float4*)(Wt + (size_t)k * DD);
    const float4* wc  = (const float4*)(Wpair + 2 * DD);
    float s = 0.f;
#pragma unroll
    for (int i = 0; i < 4; ++i) s += dot4(row[i * 64 + lane], wc[i * 64 + lane]);
#pragma unroll
    for (int off = 32; off; off >>= 1) s += __shfl_down(s, off, 64);
    if (lane == 0) v[k] = s;
}

// ---------- kernel: per-batch scalars ----------
__global__ void k_scalars(const float* __restrict__ relation, const float* __restrict__ subject,
                          const float* __restrict__ obj, const float* __restrict__ btheta,
                          const float* __restrict__ Wpair, const float* __restrict__ bpair,
                          const float* __restrict__ Wcls, const float* __restrict__ bcls,
                          const float* __restrict__ v,
                          float* __restrict__ relt, float* __restrict__ subc,
                          float* __restrict__ objc) {
    __shared__ float red[4];
    int wave = threadIdx.x >> 6, lane = threadIdx.x & 63;
    int b = blockIdx.x;
    const float4* aa;
    const float4* bb;
    if (wave == 0)      { aa = (const float4*)(relation + (size_t)b * DD); bb = (const float4*)v; }
    else if (wave == 1) { aa = (const float4*)(subject + (size_t)b * DD);  bb = (const float4*)(Wcls + DD); }
    else if (wave == 2) { aa = (const float4*)(obj + (size_t)b * DD);      bb = (const float4*)(Wcls + DD); }
    else                { aa = (const float4*)btheta;                      bb = (const float4*)(Wpair + 2 * DD); }
    float s = 0.f;
#pragma unroll
    for (int i = 0; i < 4; ++i) s += dot4(aa[i * 64 + lane], bb[i * 64 + lane]);
#pragma unroll
    for (int off = 32; off; off >>= 1) s += __shfl_down(s, off, 64);
    if (lane == 0) red[wave] = s;
    __syncthreads();
    if (threadIdx.x == 0) {
        relt[b] = red[0] + red[3] + bpair[0];
        subc[b] = red[1] + bcls[0];
        objc[b] = red[2] + bcls[0];
    }
}

// ---------- kernel: per-row dots + outputs (blocks 0..4799) + W_bbox transpose (4800..5439) ----------
// Both bodies are verbatim the R4-verified k_rows and k_prep-transpose; only the grid
// placement changed (transpose rides inside the k_rows launch, disjoint block range).
template<int WB>
__global__ __launch_bounds__(256) void k_rows_t(
        const float* __restrict__ x, const float* __restrict__ Wpair,
        const float* __restrict__ Wcls,
        const float* __restrict__ relt, const float* __restrict__ subc,
        const float* __restrict__ objc,
        float* __restrict__ colv, float* __restrict__ rowp,
        float* __restrict__ sarr, float* __restrict__ oarr,
        float* __restrict__ out, u16* __restrict__ xb,
        const float* __restrict__ Wbbox, u16* __restrict__ Bt) {
    __shared__ float tile[32][33];
    if (blockIdx.x >= 4800) {
        // transpose+pad W_bbox (1024x604 f32) -> Bt (640x1024 bf16)
        int blk = blockIdx.x - 4800;    // 0..639
        int tid = threadIdx.x;
        int k0 = (blk & 31) * 32;
        int n0 = (blk >> 5) * 32;
        int tx = tid & 31;          // 0..31
        int ty = tid >> 5;          // 0..7
#pragma unroll
        for (int i = 0; i < 4; ++i) {
            int k = k0 + ty + i * 8;
            int n = n0 + tx;
            tile[ty + i * 8][tx] = (n < NOUT) ? Wbbox[(size_t)k * NOUT + n] : 0.f;
        }
        __syncthreads();
#pragma unroll
        for (int i = 0; i < 4; ++i) {
            int n = n0 + ty + i * 8;
            int k = k0 + tx;
            Bt[(size_t)n * DD + k] = f2bf(tile[tx][ty + i * 8]);
        }
        return;
    }
    int wave = threadIdx.x >> 6, lane = threadIdx.x & 63;
    int r = blockIdx.x * 4 + wave;                // 0..19199
    const float4* xr = (const float4*)(x + (size_t)r * DD);
    const float4* wa = (const float4*)(Wpair);
    const float4* wb = (const float4*)(Wpair + DD);
    const float4* w1 = (const float4*)(Wcls);
    float ca = 0.f, cb = 0.f, cw = 0.f;
#pragma unroll
    for (int i = 0; i < 4; ++i) {
        int idx = i * 64 + lane;
        float4 xv = xr[idx];
        ca += dot4(xv, wa[idx]);
        cb += dot4(xv, wb[idx]);
        cw += dot4(xv, w1[idx]);
        if (WB) {
            // truncate fp32 -> bf16 (identical numerics to the fallback GEMM's in-kernel perm)
            unsigned lo = __builtin_amdgcn_perm(__float_as_uint(xv.y), __float_as_uint(xv.x), 0x07060302u);
            unsigned hi = __builtin_amdgcn_perm(__float_as_uint(xv.w), __float_as_uint(xv.z), 0x07060302u);
            *(uint2*)(xb + (size_t)r * DD + idx * 4) = make_uint2(lo, hi);
        }
    }
#pragma unroll
    for (int off = 32; off; off >>= 1) {
        ca += __shfl_down(ca, off, 64);
        cb += __shfl_down(cb, off, 64);
        cw += __shfl_down(cw, off, 64);
    }
    if (lane == 0) {
        int b = r / 300;
        float s = sigmoidf(cw + subc[b]);
        float o = sigmoidf(cw + objc[b]);
        colv[r] = ca;
        rowp[r] = cb + relt[b];
        sarr[r] = s;
        oarr[r] = o;
        ((float2*)out)[r]         = make_float2(1.f - s, s);   // x_subj pair (fp32)
        ((float2*)out)[NROWS + r] = make_float2(1.f - o, o);   // x_obj pair (fp32)
    }
}

// ---------- kernel: fused bbox-GEMM (blocks 0..759) + pair_score (blocks 760..2679) ----------
// R4-VERIFIED body, restored verbatim. 128x128 tile, bf16 A from workspace, XOR-swizzled
// LDS (conflicts=0), double-buffered, counted-vmcnt barriers (vmcnt(8)).
#define BKK 64
#define NSTEP 16           // DD/BKK

#define WAITCNT_VM(N) asm volatile("s_waitcnt vmcnt(" #N ")" ::: "memory")

#define STAGE_TILE(buf, k0)                                                                  \
    _Pragma("unroll")                                                                        \
    for (int q = 0; q < 4; ++q) {                                                            \
        int rowblk = q * 32 + wave * 8;                                                      \
        const u16* ga = a_base + (size_t)(rowblk + s_row) * DD + (k0) + s_c16 * 8;           \
        __builtin_amdgcn_global_load_lds((const GLOBAL_AS unsigned int*)ga,                  \
                                         (LDS_AS unsigned int*)(As[buf] + rowblk * BKK),     \
                                         16, 0, 0);                                          \
        const u16* gb = b_base + (size_t)(rowblk + s_row) * DD + (k0) + s_c16 * 8;           \
        __builtin_amdgcn_global_load_lds((const GLOBAL_AS unsigned int*)gb,                  \
                                         (LDS_AS unsigned int*)(Bs[buf] + rowblk * BKK),     \
                                         16, 0, 0);                                          \
    }

#define COMPUTE_TILE(buf)                                                                    \
    _Pragma("unroll")                                                                        \
    for (int kk = 0; kk < BKK; kk += 32) {                                                   \
        bf16x8 af[4], bfv[4];                                                                \
        int cx = (((kk >> 3) + quad) ^ (l16 & 7)) * 8;                                       \
        _Pragma("unroll")                                                                    \
        for (int f = 0; f < 4; ++f) {                                                        \
            int m = wr * 64 + f * 16 + l16;                                                  \
            af[f] = *(const bf16x8*)(As[buf] + m * BKK + cx);                                \
            int n = wc * 64 + f * 16 + l16;                                                  \
            bfv[f] = *(const bf16x8*)(Bs[buf] + n * BKK + cx);                               \
        }                                                                                    \
        _Pragma("unroll")                                                                    \
        for (int fi = 0; fi < 4; ++fi)                                                       \
            _Pragma("unroll")                                                                \
            for (int fj = 0; fj < 4; ++fj)                                                   \
                acc[fi][fj] = __builtin_amdgcn_mfma_f32_16x16x32_bf16(                       \
                    af[fi], bfv[fj], acc[fi][fj], 0, 0, 0);                                  \
    }

__global__ __launch_bounds__(256) void k_fused(
        const u16* __restrict__ xb, const u16* __restrict__ bt,
        const float* __restrict__ bias, float* __restrict__ outb,
        const float* __restrict__ rowp, const float* __restrict__ colv,
        const float* __restrict__ sarr, const float* __restrict__ oarr,
        float* __restrict__ pout) {
    __shared__ u16 As[2][128 * BKK] __attribute__((aligned(16)));
    __shared__ u16 Bs[2][128 * BKK] __attribute__((aligned(16)));

    int gbid = blockIdx.x;
    if (gbid < 760) {
        // ---------------- GEMM path ----------------
        int xcd = gbid & 7;
        int rest = gbid >> 3;
        int n_t = rest % 5;
        int m_t = (rest / 5) * 8 + xcd;
        if (m_t >= 150) return;

        int tid = threadIdx.x;
        int wave = tid >> 6;
        int lane = tid & 63;
        int wr = wave >> 1, wc = wave & 1;
        int quad = lane >> 4;
        int l16 = lane & 15;

        f32x4 acc[4][4] = {};

        const u16* a_base = xb + (size_t)m_t * 128 * DD;
        const u16* b_base = bt + (size_t)n_t * 128 * DD;
        int s_row = lane >> 3;              // 0..7 (row within 8-row staging block)
        int s_c16 = (lane & 7) ^ s_row;     // pre-swizzled source 16B-chunk (XOR involution)

        STAGE_TILE(0, 0)

#pragma unroll 1
        for (int t = 0; t < NSTEP; t += 2) {
            // even half-step: stage t+1 into buf1; wait own old-8 (buf0) only; compute buf0
            STAGE_TILE(1, (t + 1) * BKK)
            WAITCNT_VM(8);
            __builtin_amdgcn_s_barrier();
            COMPUTE_TILE(0)
            __builtin_amdgcn_s_barrier();    // all waves done reading buf0 (ds_reads complete pre-MFMA)
            // odd half-step: stage t+2 into buf0 (if any); wait buf1's loads; compute buf1
            if (t + 2 < NSTEP) {
                STAGE_TILE(0, (t + 2) * BKK)
                WAITCNT_VM(8);
            } else {
                WAITCNT_VM(0);
            }
            __builtin_amdgcn_s_barrier();
            COMPUTE_TILE(1)
            __builtin_amdgcn_s_barrier();
        }

        // epilogue: add bias, mask col<604, store fp32
#pragma unroll
        for (int fj = 0; fj < 4; ++fj) {
            int col = n_t * 128 + wc * 64 + fj * 16 + l16;
            if (col < NOUT) {
                float bia = bias[col];
#pragma unroll
                for (int fi = 0; fi < 4; ++fi) {
#pragma unroll
                    for (int rg = 0; rg < 4; ++rg) {
                        int row = m_t * 128 + wr * 64 + fi * 16 + quad * 4 + rg;
                        outb[(size_t)row * NOUT + col] = acc[fi][fj][rg] + bia;
                    }
                }
            }
        }
    } else {
        // ---------------- pair_score path (independent work; hides under GEMM) ----------------
        float* cb_s = (float*)As;            // alias LDS (disjoint block paths)
        float* ob_s = ((float*)As) + 300;
        int blk = gbid - 760;                // 0..1919
        int b = blk / 30;
        int chunk = blk - b * 30;            // 0..29
        int r0 = b * 300 + chunk * 10;
        int tid = threadIdx.x;
        for (int j = tid; j < 300; j += 256) {
            cb_s[j] = colv[b * 300 + j];
            ob_s[j] = oarr[b * 300 + j];
        }
        __syncthreads();
        if (tid < 150) {
            float c0 = cb_s[2 * tid], c1 = cb_s[2 * tid + 1];
            float o0 = ob_s[2 * tid], o1 = ob_s[2 * tid + 1];
#pragma unroll
            for (int rr = 0; rr < 10; ++rr) {
                int r = r0 + rr;
                float rp = rowp[r];
                float ss = sarr[r];
                float p0 = sigmoidf(rp + c0) * o0 * ss;
                float p1 = sigmoidf(rp + c1) * o1 * ss;
                ((float2*)(pout + (size_t)r * 300))[tid] = make_float2(p0, p1);
            }
        }
    }
}

// ---------- fallback kernels (small workspace): previous verified path ----------
__global__ __launch_bounds__(256) void k_prep(const float* __restrict__ Wbbox, u16* __restrict__ Bt,
                                              const float* __restrict__ Wt, const float* __restrict__ Wpair,
                                              float* __restrict__ v) {
    __shared__ float tile[32][33];
    int blk = blockIdx.x;
    int tid = threadIdx.x;
    if (blk < 640) {
        int k0 = (blk & 31) * 32;
        int n0 = (blk >> 5) * 32;
        int tx = tid & 31;
        int ty = tid >> 5;
#pragma unroll
        for (int i = 0; i < 4; ++i) {
            int k = k0 + ty + i * 8;
            int n = n0 + tx;
            tile[ty + i * 8][tx] = (n < NOUT) ? Wbbox[(size_t)k * NOUT + n] : 0.f;
        }
        __syncthreads();
#pragma unroll
        for (int i = 0; i < 4; ++i) {
            int n = n0 + ty + i * 8;
            int k = k0 + tx;
            Bt[(size_t)n * DD + k] = f2bf(tile[tx][ty + i * 8]);
        }
    } else {
        int wave = tid >> 6, lane = tid & 63;
        int k = (blk - 640) * 4 + wave;
        const float4* row = (const float4*)(Wt + (size_t)k * DD);
        const float4* wc  = (const float4*)(Wpair + 2 * DD);
        float s = 0.f;
#pragma unroll
        for (int i = 0; i < 4; ++i) s += dot4(row[i * 64 + lane], wc[i * 64 + lane]);
#pragma unroll
        for (int off = 32; off; off >>= 1) s += __shfl_down(s, off, 64);
        if (lane == 0) v[k] = s;
    }
}

__global__ __launch_bounds__(192) void k_pair_sa(
        const float* __restrict__ rowp, const float* __restrict__ colv,
        const float* __restrict__ sarr, const float* __restrict__ oarr,
        float* __restrict__ pout) {
    __shared__ float cb_s[300];
    __shared__ float ob_s[300];
    int blk = blockIdx.x;               // 0..1919
    int b = blk / 30;
    int chunk = blk - b * 30;           // 0..29
    int r0 = b * 300 + chunk * 10;
    int tid = threadIdx.x;
    for (int j = tid; j < 300; j += 192) {
        cb_s[j] = colv[b * 300 + j];
        ob_s[j] = oarr[b * 300 + j];
    }
    __syncthreads();
    if (tid < 150) {
        float c0 = cb_s[2 * tid], c1 = cb_s[2 * tid + 1];
        float o0 = ob_s[2 * tid], o1 = ob_s[2 * tid + 1];
#pragma unroll
        for (int rr = 0; rr < 10; ++rr) {
            int r = r0 + rr;
            float rp = rowp[r];
            float ss = sarr[r];
            float p0 = sigmoidf(rp + c0) * o0 * ss;
            float p1 = sigmoidf(rp + c1) * o1 * ss;
            ((float2*)(pout + (size_t)r * 300))[tid] = make_float2(p0, p1);
        }
    }
}

__global__ __launch_bounds__(256) void k_gemm(
        const float* __restrict__ x, const u16* __restrict__ bt,
        const float* __restrict__ bias, float* __restrict__ out) {
    __shared__ u16 As[128 * BKK] __attribute__((aligned(16)));
    __shared__ u16 Bs[128 * BKK] __attribute__((aligned(16)));

    int bid = blockIdx.x;
    int xcd = bid & 7;
    int rest = bid >> 3;
    int n_t = rest % 5;
    int m_t = (rest / 5) * 8 + xcd;
    if (m_t >= 150) return;

    int tid = threadIdx.x;
    int wave = tid >> 6;
    int lane = tid & 63;
    int wr = wave >> 1, wc = wave & 1;
    int quad = lane >> 4;
    int l16 = lane & 15;

    f32x4 acc[4][4] = {};

    const float* a_base = x  + (size_t)m_t * 128 * DD;
    const u16*   b_base = bt + (size_t)n_t * 128 * DD;
    int s_row = lane >> 3;
    int s_c16 = lane & 7;
    int arow8 = tid >> 4;
    int acol4 = tid & 15;

    for (int k0 = 0; k0 < DD; k0 += BKK) {
#pragma unroll
        for (int q = 0; q < 4; ++q) {
            int rowblk = q * 32 + wave * 8;
            const u16* gb = b_base + (size_t)(rowblk + s_row) * DD + k0 + s_c16 * 8;
            __builtin_amdgcn_global_load_lds((const GLOBAL_AS unsigned int*)gb,
                                             (LDS_AS unsigned int*)(Bs + rowblk * BKK),
                                             16, 0, 0);
        }
#pragma unroll
        for (int it = 0; it < 8; ++it) {
            int row = it * 16 + arow8;
            float4 av = *(const float4*)(a_base + (size_t)row * DD + k0 + acol4 * 4);
            unsigned lo = __builtin_amdgcn_perm(__float_as_uint(av.y), __float_as_uint(av.x), 0x07060302u);
            unsigned hi = __builtin_amdgcn_perm(__float_as_uint(av.w), __float_as_uint(av.z), 0x07060302u);
            *(uint2*)(As + row * BKK + acol4 * 4) = make_uint2(lo, hi);
        }
        __syncthreads();
#pragma unroll
        for (int kk = 0; kk < BKK; kk += 32) {
            bf16x8 af[4], bfv[4];
#pragma unroll
            for (int f = 0; f < 4; ++f) {
                int m = wr * 64 + f * 16 + l16;
                af[f] = *(const bf16x8*)(As + m * BKK + kk + quad * 8);
                int n = wc * 64 + f * 16 + l16;
                bfv[f] = *(const bf16x8*)(Bs + n * BKK + kk + quad * 8);
            }
#pragma unroll
            for (int fi = 0; fi < 4; ++fi)
#pragma unroll
                for (int fj = 0; fj < 4; ++fj)
                    acc[fi][fj] = __builtin_amdgcn_mfma_f32_16x16x32_bf16(
                        af[fi], bfv[fj], acc[fi][fj], 0, 0, 0);
        }
        __syncthreads();
    }

#pragma unroll
    for (int fj = 0; fj < 4; ++fj) {
        int col = n_t * 128 + wc * 64 + fj * 16 + l16;
        if (col < NOUT) {
            float bia = bias[col];
#pragma unroll
            for (int fi = 0; fi < 4; ++fi) {
#pragma unroll
                for (int rg = 0; rg < 4; ++rg) {
                    int row = m_t * 128 + wr * 64 + fi * 16 + quad * 4 + rg;
                    out[(size_t)row * NOUT + col] = acc[fi][fj][rg] + bia;
                }
            }
        }
    }
}

extern "C" void kernel_launch(void* const* d_in, const int* in_sizes, int n_in,
                              void* d_out, int out_size, void* d_ws, size_t ws_size,
                              hipStream_t stream) {
    // ---- input binding by element counts (proven equivalent to dict order) ----
    const void* P[12] = {};
    int sv[3] = {-1, -1, -1}; int nsv = 0;
    int sc[2] = {-1, -1};     int nsc = 0;
    for (int i = 0; i < n_in; ++i) {
        switch (in_sizes[i]) {
            case 19660800: P[0]  = d_in[i]; break;
            case 65536:    if (nsv < 3) sv[nsv++] = i; break;
            case 1048576:  P[4]  = d_in[i]; break;
            case 1024:     P[5]  = d_in[i]; break;
            case 3072:     P[6]  = d_in[i]; break;
            case 1:        if (nsc < 2) sc[nsc++] = i; break;
            case 2048:     P[8]  = d_in[i]; break;
            case 618496:   P[10] = d_in[i]; break;
            case 604:      P[11] = d_in[i]; break;
            default: break;
        }
    }
    bool alpha = (n_in == 12 && in_sizes[0] == 618496);
    if (alpha) {
        P[2] = d_in[sv[0]]; P[3] = d_in[sv[1]]; P[1] = d_in[sv[2]];
        P[9] = d_in[sc[0]]; P[7] = d_in[sc[1]];
    } else {
        P[1] = d_in[sv[0]]; P[2] = d_in[sv[1]]; P[3] = d_in[sv[2]];
        P[7] = d_in[sc[0]]; P[9] = d_in[sc[1]];
    }
    const float* x        = (const float*)P[0];
    const float* subject  = (const float*)P[1];
    const float* obj      = (const float*)P[2];
    const float* relation = (const float*)P[3];
    const float* W_theta  = (const float*)P[4];
    const float* b_theta  = (const float*)P[5];
    const float* W_pair   = (const float*)P[6];
    const float* b_pair   = (const float*)P[7];
    const float* W_cls    = (const float*)P[8];
    const float* b_cls    = (const float*)P[9];
    const float* W_bbox   = (const float*)P[10];
    const float* b_bbox   = (const float*)P[11];
    float* out = (float*)d_out;

    // ws layout
    char* ws = (char*)d_ws;
    float* v    = (float*)(ws + 0);         // 1024 f32
    float* relt = (float*)(ws + 4096);      // 64 f32
    float* subc = (float*)(ws + 4352);      // 64 f32
    float* objc = (float*)(ws + 4608);      // 64 f32
    float* colv = (float*)(ws + 4864);      // 19200 f32
    float* rowp = (float*)(ws + 81664);     // 19200 f32
    float* sarr = (float*)(ws + 158464);    // 19200 f32
    float* oarr = (float*)(ws + 235264);    // 19200 f32 (end 312,064)
    u16*   Bt   = (u16*)(ws + 312064);      // 640*1024 bf16 = 1,310,720 B (end 1,622,784)
    u16*   Xb   = (u16*)(ws + 1622784);     // 19200*1024 bf16 = 39,321,600 B (end 40,944,384)

    const size_t WS_NEED_BF16 = 40944384;
    bool big_ws = (ws_size >= WS_NEED_BF16);

    if (big_ws) {
        k_vtheta<<<256, 256, 0, stream>>>(W_theta, W_pair, v);
        k_scalars<<<64, 256, 0, stream>>>(relation, subject, obj, b_theta, W_pair, b_pair,
                                          W_cls, b_cls, v, relt, subc, objc);
        k_rows_t<1><<<5440, 256, 0, stream>>>(x, W_pair, W_cls, relt, subc, objc,
                                              colv, rowp, sarr, oarr, out, Xb, W_bbox, Bt);
        k_fused<<<2680, 256, 0, stream>>>(Xb, Bt, b_bbox, out + OFF_BBOX,
                                          rowp, colv, sarr, oarr, out + OFF_PAIR);
    } else {
        k_prep<<<896, 256, 0, stream>>>(W_bbox, Bt, W_theta, W_pair, v);
        k_scalars<<<64, 256, 0, stream>>>(relation, subject, obj, b_theta, W_pair, b_pair,
                                          W_cls, b_cls, v, relt, subc, objc);
        k_rows_t<0><<<4800, 256, 0, stream>>>(x, W_pair, W_cls, relt, subc, objc,
                                              colv, rowp, sarr, oarr, out, nullptr, W_bbox, Bt);
        k_pair_sa<<<1920, 192, 0, stream>>>(rowp, colv, sarr, oarr, out + OFF_PAIR);
        k_gemm<<<760, 256, 0, stream>>>(x, Bt, b_bbox, out + OFF_BBOX);
    }
}

// Round 7
// 204.352 us; speedup vs baseline: 1.1444x; 1.0015x over previous
//
#include <hip/hip_runtime.h>

// ---------- constants ----------
#define PP    300
#define DD    1024
#define NOUT  604          // (150+1)*4
#define NROWS 19200        // 64*300
// output element offsets (fp32 elements)
#define OFF_PAIR  76800
#define OFF_BBOX  5836800  // 76800 + 64*300*300

typedef unsigned short u16;
typedef __attribute__((ext_vector_type(8))) short bf16x8;
typedef __attribute__((ext_vector_type(4))) float f32x4;

#define GLOBAL_AS __attribute__((address_space(1)))
#define LDS_AS    __attribute__((address_space(3)))

__device__ inline u16 f2bf(float f) {
    unsigned u = __float_as_uint(f);
    return (u16)((u + 0x7fffu + ((u >> 16) & 1u)) >> 16);
}
__device__ inline float dot4(float4 a, float4 b) {
    return fmaf(a.x, b.x, fmaf(a.y, b.y, fmaf(a.z, b.z, a.w * b.w)));
}
__device__ inline float sigmoidf(float z) { return 1.f / (1.f + __expf(-z)); }

// ---------- kernel: v = W_theta @ Wc  (Wc = W_pair[2048:3072]) ----------
__global__ void k_vtheta(const float* __restrict__ Wt, const float* __restrict__ Wpair,
                         float* __restrict__ v) {
    int wave = threadIdx.x >> 6, lane = threadIdx.x & 63;
    int k = blockIdx.x * 4 + wave;                // 0..1023
    const float4* row = (const float4*)(Wt + (size_t)k * DD);
    const float4* wc  = (const float4*)(Wpair + 2 * DD);
    float s = 0.f;
#pragma unroll
    for (int i = 0; i < 4; ++i) s += dot4(row[i * 64 + lane], wc[i * 64 + lane]);
#pragma unroll
    for (int off = 32; off; off >>= 1) s += __shfl_down(s, off, 64);
    if (lane == 0) v[k] = s;
}

// ---------- kernel: per-batch scalars ----------
__global__ void k_scalars(const float* __restrict__ relation, const float* __restrict__ subject,
                          const float* __restrict__ obj, const float* __restrict__ btheta,
                          const float* __restrict__ Wpair, const float* __restrict__ bpair,
                          const float* __restrict__ Wcls, const float* __restrict__ bcls,
                          const float* __restrict__ v,
                          float* __restrict__ relt, float* __restrict__ subc,
                          float* __restrict__ objc) {
    __shared__ float red[4];
    int wave = threadIdx.x >> 6, lane = threadIdx.x & 63;
    int b = blockIdx.x;
    const float4* aa;
    const float4* bb;
    if (wave == 0)      { aa = (const float4*)(relation + (size_t)b * DD); bb = (const float4*)v; }
    else if (wave == 1) { aa = (const float4*)(subject + (size_t)b * DD);  bb = (const float4*)(Wcls + DD); }
    else if (wave == 2) { aa = (const float4*)(obj + (size_t)b * DD);      bb = (const float4*)(Wcls + DD); }
    else                { aa = (const float4*)btheta;                      bb = (const float4*)(Wpair + 2 * DD); }
    float s = 0.f;
#pragma unroll
    for (int i = 0; i < 4; ++i) s += dot4(aa[i * 64 + lane], bb[i * 64 + lane]);
#pragma unroll
    for (int off = 32; off; off >>= 1) s += __shfl_down(s, off, 64);
    if (lane == 0) red[wave] = s;
    __syncthreads();
    if (threadIdx.x == 0) {
        relt[b] = red[0] + red[3] + bpair[0];
        subc[b] = red[1] + bcls[0];
        objc[b] = red[2] + bcls[0];
    }
}

// ---------- kernel: per-row dots + outputs (blocks 0..4799) + W_bbox transpose (4800..5439) ----------
// Verbatim R6-verified.
template<int WB>
__global__ __launch_bounds__(256) void k_rows_t(
        const float* __restrict__ x, const float* __restrict__ Wpair,
        const float* __restrict__ Wcls,
        const float* __restrict__ relt, const float* __restrict__ subc,
        const float* __restrict__ objc,
        float* __restrict__ colv, float* __restrict__ rowp,
        float* __restrict__ sarr, float* __restrict__ oarr,
        float* __restrict__ out, u16* __restrict__ xb,
        const float* __restrict__ Wbbox, u16* __restrict__ Bt) {
    __shared__ float tile[32][33];
    if (blockIdx.x >= 4800) {
        // transpose+pad W_bbox (1024x604 f32) -> Bt (640x1024 bf16)
        int blk = blockIdx.x - 4800;    // 0..639
        int tid = threadIdx.x;
        int k0 = (blk & 31) * 32;
        int n0 = (blk >> 5) * 32;
        int tx = tid & 31;          // 0..31
        int ty = tid >> 5;          // 0..7
#pragma unroll
        for (int i = 0; i < 4; ++i) {
            int k = k0 + ty + i * 8;
            int n = n0 + tx;
            tile[ty + i * 8][tx] = (n < NOUT) ? Wbbox[(size_t)k * NOUT + n] : 0.f;
        }
        __syncthreads();
#pragma unroll
        for (int i = 0; i < 4; ++i) {
            int n = n0 + ty + i * 8;
            int k = k0 + tx;
            Bt[(size_t)n * DD + k] = f2bf(tile[tx][ty + i * 8]);
        }
        return;
    }
    int wave = threadIdx.x >> 6, lane = threadIdx.x & 63;
    int r = blockIdx.x * 4 + wave;                // 0..19199
    const float4* xr = (const float4*)(x + (size_t)r * DD);
    const float4* wa = (const float4*)(Wpair);
    const float4* wb = (const float4*)(Wpair + DD);
    const float4* w1 = (const float4*)(Wcls);
    float ca = 0.f, cb = 0.f, cw = 0.f;
#pragma unroll
    for (int i = 0; i < 4; ++i) {
        int idx = i * 64 + lane;
        float4 xv = xr[idx];
        ca += dot4(xv, wa[idx]);
        cb += dot4(xv, wb[idx]);
        cw += dot4(xv, w1[idx]);
        if (WB) {
            // truncate fp32 -> bf16 (identical numerics to the fallback GEMM's in-kernel perm)
            unsigned lo = __builtin_amdgcn_perm(__float_as_uint(xv.y), __float_as_uint(xv.x), 0x07060302u);
            unsigned hi = __builtin_amdgcn_perm(__float_as_uint(xv.w), __float_as_uint(xv.z), 0x07060302u);
            *(uint2*)(xb + (size_t)r * DD + idx * 4) = make_uint2(lo, hi);
        }
    }
#pragma unroll
    for (int off = 32; off; off >>= 1) {
        ca += __shfl_down(ca, off, 64);
        cb += __shfl_down(cb, off, 64);
        cw += __shfl_down(cw, off, 64);
    }
    if (lane == 0) {
        int b = r / 300;
        float s = sigmoidf(cw + subc[b]);
        float o = sigmoidf(cw + objc[b]);
        colv[r] = ca;
        rowp[r] = cb + relt[b];
        sarr[r] = s;
        oarr[r] = o;
        ((float2*)out)[r]         = make_float2(1.f - s, s);   // x_subj pair (fp32)
        ((float2*)out)[NROWS + r] = make_float2(1.f - o, o);   // x_obj pair (fp32)
    }
}

// ---------- kernel: fused bbox-GEMM (blocks 0..1519) + pair_score (blocks 1520..3439) ----------
// R7 change (ISOLATED): GEMM tile 128x128 -> 128x64. LDS 64KB -> 48KB => 3 blocks/CU
// (12 waves/CU, was 8); active blocks 600 -> 1500 (finer tail). acc 4x4 -> 2x4.
// 6 staged loads/wave/K-step -> vmcnt(6). All other machinery (XOR swizzle, dbuf,
// counted-vmcnt barriers) and the PAIR PATH are verbatim the R6-verified code.
#define BKK 64
#define NSTEP 16           // DD/BKK

#define WAITCNT_VM(N) asm volatile("s_waitcnt vmcnt(" #N ")" ::: "memory")

// per K-step per wave: 4 A-loads (128 rows) + 2 B-loads (64 rows)
#define STAGE_TILE(buf, k0)                                                                  \
    _Pragma("unroll")                                                                        \
    for (int q = 0; q < 4; ++q) {                                                            \
        int rowblk = q * 32 + wave * 8;                                                      \
        const u16* ga = a_base + (size_t)(rowblk + s_row) * DD + (k0) + s_c16 * 8;           \
        __builtin_amdgcn_global_load_lds((const GLOBAL_AS unsigned int*)ga,                  \
                                         (LDS_AS unsigned int*)(As[buf] + rowblk * BKK),     \
                                         16, 0, 0);                                          \
    }                                                                                        \
    _Pragma("unroll")                                                                        \
    for (int q = 0; q < 2; ++q) {                                                            \
        int rowblk = q * 32 + wave * 8;                                                      \
        const u16* gb = b_base + (size_t)(rowblk + s_row) * DD + (k0) + s_c16 * 8;           \
        __builtin_amdgcn_global_load_lds((const GLOBAL_AS unsigned int*)gb,                  \
                                         (LDS_AS unsigned int*)(Bs[buf] + rowblk * BKK),     \
                                         16, 0, 0);                                          \
    }

#define COMPUTE_TILE(buf)                                                                    \
    _Pragma("unroll")                                                                        \
    for (int kk = 0; kk < BKK; kk += 32) {                                                   \
        bf16x8 af[2], bfv[4];                                                                \
        int cx = (((kk >> 3) + quad) ^ (l16 & 7)) * 8;                                       \
        _Pragma("unroll")                                                                    \
        for (int f = 0; f < 2; ++f) {                                                        \
            int m = wave * 32 + f * 16 + l16;                                                \
            af[f] = *(const bf16x8*)(As[buf] + m * BKK + cx);                                \
        }                                                                                    \
        _Pragma("unroll")                                                                    \
        for (int f = 0; f < 4; ++f) {                                                        \
            int n = f * 16 + l16;                                                            \
            bfv[f] = *(const bf16x8*)(Bs[buf] + n * BKK + cx);                               \
        }                                                                                    \
        _Pragma("unroll")                                                                    \
        for (int fi = 0; fi < 2; ++fi)                                                       \
            _Pragma("unroll")                                                                \
            for (int fj = 0; fj < 4; ++fj)                                                   \
                acc[fi][fj] = __builtin_amdgcn_mfma_f32_16x16x32_bf16(                       \
                    af[fi], bfv[fj], acc[fi][fj], 0, 0, 0);                                  \
    }

#define GEMM_BLOCKS 1520   // 8 xcd * 10 n_t * 19 m-groups (active: 150*10 = 1500)

__global__ __launch_bounds__(256) void k_fused(
        const u16* __restrict__ xb, const u16* __restrict__ bt,
        const float* __restrict__ bias, float* __restrict__ outb,
        const float* __restrict__ rowp, const float* __restrict__ colv,
        const float* __restrict__ sarr, const float* __restrict__ oarr,
        float* __restrict__ pout) {
    __shared__ u16 As[2][128 * BKK] __attribute__((aligned(16)));
    __shared__ u16 Bs[2][64 * BKK]  __attribute__((aligned(16)));

    int gbid = blockIdx.x;
    if (gbid < GEMM_BLOCKS) {
        // ---------------- GEMM path: 128m x 64n ----------------
        int xcd = gbid & 7;
        int rest = gbid >> 3;
        int n_t = rest % 10;                 // 0..9 (64-col tiles over 640)
        int m_t = (rest / 10) * 8 + xcd;     // 0..151
        if (m_t >= 150) return;

        int tid = threadIdx.x;
        int wave = tid >> 6;
        int lane = tid & 63;
        int quad = lane >> 4;
        int l16 = lane & 15;

        f32x4 acc[2][4] = {};

        const u16* a_base = xb + (size_t)m_t * 128 * DD;
        const u16* b_base = bt + (size_t)n_t * 64 * DD;
        int s_row = lane >> 3;              // 0..7 (row within 8-row staging block)
        int s_c16 = (lane & 7) ^ s_row;     // pre-swizzled source 16B-chunk (XOR involution)

        STAGE_TILE(0, 0)

#pragma unroll 1
        for (int t = 0; t < NSTEP; t += 2) {
            // even half-step: stage t+1 into buf1; wait own old-6 (buf0) only; compute buf0
            STAGE_TILE(1, (t + 1) * BKK)
            WAITCNT_VM(6);
            __builtin_amdgcn_s_barrier();
            COMPUTE_TILE(0)
            __builtin_amdgcn_s_barrier();    // all waves done reading buf0
            // odd half-step: stage t+2 into buf0 (if any); wait buf1's loads; compute buf1
            if (t + 2 < NSTEP) {
                STAGE_TILE(0, (t + 2) * BKK)
                WAITCNT_VM(6);
            } else {
                WAITCNT_VM(0);
            }
            __builtin_amdgcn_s_barrier();
            COMPUTE_TILE(1)
            __builtin_amdgcn_s_barrier();
        }

        // epilogue: add bias, mask col<604, store fp32
#pragma unroll
        for (int fj = 0; fj < 4; ++fj) {
            int col = n_t * 64 + fj * 16 + l16;
            if (col < NOUT) {
                float bia = bias[col];
#pragma unroll
                for (int fi = 0; fi < 2; ++fi) {
#pragma unroll
                    for (int rg = 0; rg < 4; ++rg) {
                        int row = m_t * 128 + wave * 32 + fi * 16 + quad * 4 + rg;
                        outb[(size_t)row * NOUT + col] = acc[fi][fj][rg] + bia;
                    }
                }
            }
        }
    } else {
        // ---------------- pair_score path (verbatim R6) ----------------
        float* cb_s = (float*)As;            // alias LDS (disjoint block paths)
        float* ob_s = ((float*)As) + 300;
        int blk = gbid - GEMM_BLOCKS;        // 0..1919
        int b = blk / 30;
        int chunk = blk - b * 30;            // 0..29
        int r0 = b * 300 + chunk * 10;
        int tid = threadIdx.x;
        for (int j = tid; j < 300; j += 256) {
            cb_s[j] = colv[b * 300 + j];
            ob_s[j] = oarr[b * 300 + j];
        }
        __syncthreads();
        if (tid < 150) {
            float c0 = cb_s[2 * tid], c1 = cb_s[2 * tid + 1];
            float o0 = ob_s[2 * tid], o1 = ob_s[2 * tid + 1];
#pragma unroll
            for (int rr = 0; rr < 10; ++rr) {
                int r = r0 + rr;
                float rp = rowp[r];
                float ss = sarr[r];
                float p0 = sigmoidf(rp + c0) * o0 * ss;
                float p1 = sigmoidf(rp + c1) * o1 * ss;
                ((float2*)(pout + (size_t)r * 300))[tid] = make_float2(p0, p1);
            }
        }
    }
}

// ---------- fallback kernels (small workspace): previous verified path ----------
__global__ __launch_bounds__(256) void k_prep(const float* __restrict__ Wbbox, u16* __restrict__ Bt,
                                              const float* __restrict__ Wt, const float* __restrict__ Wpair,
                                              float* __restrict__ v) {
    __shared__ float tile[32][33];
    int blk = blockIdx.x;
    int tid = threadIdx.x;
    if (blk < 640) {
        int k0 = (blk & 31) * 32;
        int n0 = (blk >> 5) * 32;
        int tx = tid & 31;
        int ty = tid >> 5;
#pragma unroll
        for (int i = 0; i < 4; ++i) {
            int k = k0 + ty + i * 8;
            int n = n0 + tx;
            tile[ty + i * 8][tx] = (n < NOUT) ? Wbbox[(size_t)k * NOUT + n] : 0.f;
        }
        __syncthreads();
#pragma unroll
        for (int i = 0; i < 4; ++i) {
            int n = n0 + ty + i * 8;
            int k = k0 + tx;
            Bt[(size_t)n * DD + k] = f2bf(tile[tx][ty + i * 8]);
        }
    } else {
        int wave = tid >> 6, lane = tid & 63;
        int k = (blk - 640) * 4 + wave;
        const float4* row = (const float4*)(Wt + (size_t)k * DD);
        const float4* wc  = (const float4*)(Wpair + 2 * DD);
        float s = 0.f;
#pragma unroll
        for (int i = 0; i < 4; ++i) s += dot4(row[i * 64 + lane], wc[i * 64 + lane]);
#pragma unroll
        for (int off = 32; off; off >>= 1) s += __shfl_down(s, off, 64);
        if (lane == 0) v[k] = s;
    }
}

__global__ __launch_bounds__(192) void k_pair_sa(
        const float* __restrict__ rowp, const float* __restrict__ colv,
        const float* __restrict__ sarr, const float* __restrict__ oarr,
        float* __restrict__ pout) {
    __shared__ float cb_s[300];
    __shared__ float ob_s[300];
    int blk = blockIdx.x;               // 0..1919
    int b = blk / 30;
    int chunk = blk - b * 30;           // 0..29
    int r0 = b * 300 + chunk * 10;
    int tid = threadIdx.x;
    for (int j = tid; j < 300; j += 192) {
        cb_s[j] = colv[b * 300 + j];
        ob_s[j] = oarr[b * 300 + j];
    }
    __syncthreads();
    if (tid < 150) {
        float c0 = cb_s[2 * tid], c1 = cb_s[2 * tid + 1];
        float o0 = ob_s[2 * tid], o1 = ob_s[2 * tid + 1];
#pragma unroll
        for (int rr = 0; rr < 10; ++rr) {
            int r = r0 + rr;
            float rp = rowp[r];
            float ss = sarr[r];
            float p0 = sigmoidf(rp + c0) * o0 * ss;
            float p1 = sigmoidf(rp + c1) * o1 * ss;
            ((float2*)(pout + (size_t)r * 300))[tid] = make_float2(p0, p1);
        }
    }
}

__global__ __launch_bounds__(256) void k_gemm(
        const float* __restrict__ x, const u16* __restrict__ bt,
        const float* __restrict__ bias, float* __restrict__ out) {
    __shared__ u16 As[128 * BKK] __attribute__((aligned(16)));
    __shared__ u16 Bs[128 * BKK] __attribute__((aligned(16)));

    int bid = blockIdx.x;
    int xcd = bid & 7;
    int rest = bid >> 3;
    int n_t = rest % 5;
    int m_t = (rest / 5) * 8 + xcd;
    if (m_t >= 150) return;

    int tid = threadIdx.x;
    int wave = tid >> 6;
    int lane = tid & 63;
    int wr = wave >> 1, wc = wave & 1;
    int quad = lane >> 4;
    int l16 = lane & 15;

    f32x4 acc[4][4] = {};

    const float* a_base = x  + (size_t)m_t * 128 * DD;
    const u16*   b_base = bt + (size_t)n_t * 128 * DD;
    int s_row = lane >> 3;
    int s_c16 = lane & 7;
    int arow8 = tid >> 4;
    int acol4 = tid & 15;

    for (int k0 = 0; k0 < DD; k0 += BKK) {
#pragma unroll
        for (int q = 0; q < 4; ++q) {
            int rowblk = q * 32 + wave * 8;
            const u16* gb = b_base + (size_t)(rowblk + s_row) * DD + k0 + s_c16 * 8;
            __builtin_amdgcn_global_load_lds((const GLOBAL_AS unsigned int*)gb,
                                             (LDS_AS unsigned int*)(Bs + rowblk * BKK),
                                             16, 0, 0);
        }
#pragma unroll
        for (int it = 0; it < 8; ++it) {
            int row = it * 16 + arow8;
            float4 av = *(const float4*)(a_base + (size_t)row * DD + k0 + acol4 * 4);
            unsigned lo = __builtin_amdgcn_perm(__float_as_uint(av.y), __float_as_uint(av.x), 0x07060302u);
            unsigned hi = __builtin_amdgcn_perm(__float_as_uint(av.w), __float_as_uint(av.z), 0x07060302u);
            *(uint2*)(As + row * BKK + acol4 * 4) = make_uint2(lo, hi);
        }
        __syncthreads();
#pragma unroll
        for (int kk = 0; kk < BKK; kk += 32) {
            bf16x8 af[4], bfv[4];
#pragma unroll
            for (int f = 0; f < 4; ++f) {
                int m = wr * 64 + f * 16 + l16;
                af[f] = *(const bf16x8*)(As + m * BKK + kk + quad * 8);
                int n = wc * 64 + f * 16 + l16;
                bfv[f] = *(const bf16x8*)(Bs + n * BKK + kk + quad * 8);
            }
#pragma unroll
            for (int fi = 0; fi < 4; ++fi)
#pragma unroll
                for (int fj = 0; fj < 4; ++fj)
                    acc[fi][fj] = __builtin_amdgcn_mfma_f32_16x16x32_bf16(
                        af[fi], bfv[fj], acc[fi][fj], 0, 0, 0);
        }
        __syncthreads();
    }

#pragma unroll
    for (int fj = 0; fj < 4; ++fj) {
        int col = n_t * 128 + wc * 64 + fj * 16 + l16;
        if (col < NOUT) {
            float bia = bias[col];
#pragma unroll
            for (int fi = 0; fi < 4; ++fi) {
#pragma unroll
                for (int rg = 0; rg < 4; ++rg) {
                    int row = m_t * 128 + wr * 64 + fi * 16 + quad * 4 + rg;
                    out[(size_t)row * NOUT + col] = acc[fi][fj][rg] + bia;
                }
            }
        }
    }
}

extern "C" void kernel_launch(void* const* d_in, const int* in_sizes, int n_in,
                              void* d_out, int out_size, void* d_ws, size_t ws_size,
                              hipStream_t stream) {
    // ---- input binding by element counts (proven equivalent to dict order) ----
    const void* P[12] = {};
    int sv[3] = {-1, -1, -1}; int nsv = 0;
    int sc[2] = {-1, -1};     int nsc = 0;
    for (int i = 0; i < n_in; ++i) {
        switch (in_sizes[i]) {
            case 19660800: P[0]  = d_in[i]; break;
            case 65536:    if (nsv < 3) sv[nsv++] = i; break;
            case 1048576:  P[4]  = d_in[i]; break;
            case 1024:     P[5]  = d_in[i]; break;
            case 3072:     P[6]  = d_in[i]; break;
            case 1:        if (nsc < 2) sc[nsc++] = i; break;
            case 2048:     P[8]  = d_in[i]; break;
            case 618496:   P[10] = d_in[i]; break;
            case 604:      P[11] = d_in[i]; break;
            default: break;
        }
    }
    bool alpha = (n_in == 12 && in_sizes[0] == 618496);
    if (alpha) {
        P[2] = d_in[sv[0]]; P[3] = d_in[sv[1]]; P[1] = d_in[sv[2]];
        P[9] = d_in[sc[0]]; P[7] = d_in[sc[1]];
    } else {
        P[1] = d_in[sv[0]]; P[2] = d_in[sv[1]]; P[3] = d_in[sv[2]];
        P[7] = d_in[sc[0]]; P[9] = d_in[sc[1]];
    }
    const float* x        = (const float*)P[0];
    const float* subject  = (const float*)P[1];
    const float* obj      = (const float*)P[2];
    const float* relation = (const float*)P[3];
    const float* W_theta  = (const float*)P[4];
    const float* b_theta  = (const float*)P[5];
    const float* W_pair   = (const float*)P[6];
    const float* b_pair   = (const float*)P[7];
    const float* W_cls    = (const float*)P[8];
    const float* b_cls    = (const float*)P[9];
    const float* W_bbox   = (const float*)P[10];
    const float* b_bbox   = (const float*)P[11];
    float* out = (float*)d_out;

    // ws layout
    char* ws = (char*)d_ws;
    float* v    = (float*)(ws + 0);         // 1024 f32
    float* relt = (float*)(ws + 4096);      // 64 f32
    float* subc = (float*)(ws + 4352);      // 64 f32
    float* objc = (float*)(ws + 4608);      // 64 f32
    float* colv = (float*)(ws + 4864);      // 19200 f32
    float* rowp = (float*)(ws + 81664);     // 19200 f32
    float* sarr = (float*)(ws + 158464);    // 19200 f32
    float* oarr = (float*)(ws + 235264);    // 19200 f32 (end 312,064)
    u16*   Bt   = (u16*)(ws + 312064);      // 640*1024 bf16 = 1,310,720 B (end 1,622,784)
    u16*   Xb   = (u16*)(ws + 1622784);     // 19200*1024 bf16 = 39,321,600 B (end 40,944,384)

    const size_t WS_NEED_BF16 = 40944384;
    bool big_ws = (ws_size >= WS_NEED_BF16);

    if (big_ws) {
        k_vtheta<<<256, 256, 0, stream>>>(W_theta, W_pair, v);
        k_scalars<<<64, 256, 0, stream>>>(relation, subject, obj, b_theta, W_pair, b_pair,
                                          W_cls, b_cls, v, relt, subc, objc);
        k_rows_t<1><<<5440, 256, 0, stream>>>(x, W_pair, W_cls, relt, subc, objc,
                                              colv, rowp, sarr, oarr, out, Xb, W_bbox, Bt);
        k_fused<<<GEMM_BLOCKS + 1920, 256, 0, stream>>>(Xb, Bt, b_bbox, out + OFF_BBOX,
                                                        rowp, colv, sarr, oarr, out + OFF_PAIR);
    } else {
        k_prep<<<896, 256, 0, stream>>>(W_bbox, Bt, W_theta, W_pair, v);
        k_scalars<<<64, 256, 0, stream>>>(relation, subject, obj, b_theta, W_pair, b_pair,
                                          W_cls, b_cls, v, relt, subc, objc);
        k_rows_t<0><<<4800, 256, 0, stream>>>(x, W_pair, W_cls, relt, subc, objc,
                                              colv, rowp, sarr, oarr, out, nullptr, W_bbox, Bt);
        k_pair_sa<<<1920, 192, 0, stream>>>(rowp, colv, sarr, oarr, out + OFF_PAIR);
        k_gemm<<<760, 256, 0, stream>>>(x, Bt, b_bbox, out + OFF_BBOX);
    }
}

// Round 8
// 202.289 us; speedup vs baseline: 1.1561x; 1.0102x over previous
//
#include <hip/hip_runtime.h>

// ---------- constants ----------
#define PP    300
#define DD    1024
#define NOUT  604          // (150+1)*4
#define NROWS 19200        // 64*300
// output element offsets (fp32 elements)
#define OFF_PAIR  76800
#define OFF_BBOX  5836800  // 76800 + 64*300*300

typedef unsigned short u16;
typedef __attribute__((ext_vector_type(8))) short bf16x8;
typedef __attribute__((ext_vector_type(4))) float f32x4;

#define GLOBAL_AS __attribute__((address_space(1)))
#define LDS_AS    __attribute__((address_space(3)))

__device__ inline u16 f2bf(float f) {
    unsigned u = __float_as_uint(f);
    return (u16)((u + 0x7fffu + ((u >> 16) & 1u)) >> 16);
}
__device__ inline float dot4(float4 a, float4 b) {
    return fmaf(a.x, b.x, fmaf(a.y, b.y, fmaf(a.z, b.z, a.w * b.w)));
}
__device__ inline float sigmoidf(float z) { return 1.f / (1.f + __expf(-z)); }

// ---------- launch 1 (big path): rows-raw (0..4799) + W_bbox transpose (4800..5439) + vtheta (5440..5695) ----------
// All three parts are mutually independent (no scalar dependency: rows writes RAW dots).
__global__ __launch_bounds__(256) void k_rows_raw(
        const float* __restrict__ x, const float* __restrict__ Wpair,
        const float* __restrict__ Wcls,
        float* __restrict__ colv, float* __restrict__ rowp,
        float* __restrict__ cwv, u16* __restrict__ xb,
        const float* __restrict__ Wbbox, u16* __restrict__ Bt,
        const float* __restrict__ Wt, float* __restrict__ v) {
    __shared__ float tile[32][33];
    if (blockIdx.x >= 5440) {
        // v = W_theta @ Wc  (Wc = W_pair[2048:3072])  [verbatim k_vtheta body]
        int wave = threadIdx.x >> 6, lane = threadIdx.x & 63;
        int k = (blockIdx.x - 5440) * 4 + wave;       // 0..1023
        const float4* row = (const float4*)(Wt + (size_t)k * DD);
        const float4* wc  = (const float4*)(Wpair + 2 * DD);
        float s = 0.f;
#pragma unroll
        for (int i = 0; i < 4; ++i) s += dot4(row[i * 64 + lane], wc[i * 64 + lane]);
#pragma unroll
        for (int off = 32; off; off >>= 1) s += __shfl_down(s, off, 64);
        if (lane == 0) v[k] = s;
        return;
    }
    if (blockIdx.x >= 4800) {
        // transpose+pad W_bbox (1024x604 f32) -> Bt (640x1024 bf16)  [verbatim]
        int blk = blockIdx.x - 4800;    // 0..639
        int tid = threadIdx.x;
        int k0 = (blk & 31) * 32;
        int n0 = (blk >> 5) * 32;
        int tx = tid & 31;          // 0..31
        int ty = tid >> 5;          // 0..7
#pragma unroll
        for (int i = 0; i < 4; ++i) {
            int k = k0 + ty + i * 8;
            int n = n0 + tx;
            tile[ty + i * 8][tx] = (n < NOUT) ? Wbbox[(size_t)k * NOUT + n] : 0.f;
        }
        __syncthreads();
#pragma unroll
        for (int i = 0; i < 4; ++i) {
            int n = n0 + ty + i * 8;
            int k = k0 + tx;
            Bt[(size_t)n * DD + k] = f2bf(tile[tx][ty + i * 8]);
        }
        return;
    }
    // per-row raw dots + bf16 x copy (no scalar dependency)
    int wave = threadIdx.x >> 6, lane = threadIdx.x & 63;
    int r = blockIdx.x * 4 + wave;                // 0..19199
    const float4* xr = (const float4*)(x + (size_t)r * DD);
    const float4* wa = (const float4*)(Wpair);
    const float4* wb = (const float4*)(Wpair + DD);
    const float4* w1 = (const float4*)(Wcls);
    float ca = 0.f, cb = 0.f, cw = 0.f;
#pragma unroll
    for (int i = 0; i < 4; ++i) {
        int idx = i * 64 + lane;
        float4 xv = xr[idx];
        ca += dot4(xv, wa[idx]);
        cb += dot4(xv, wb[idx]);
        cw += dot4(xv, w1[idx]);
        // truncate fp32 -> bf16 (identical numerics to fallback GEMM's in-kernel perm)
        unsigned lo = __builtin_amdgcn_perm(__float_as_uint(xv.y), __float_as_uint(xv.x), 0x07060302u);
        unsigned hi = __builtin_amdgcn_perm(__float_as_uint(xv.w), __float_as_uint(xv.z), 0x07060302u);
        *(uint2*)(xb + (size_t)r * DD + idx * 4) = make_uint2(lo, hi);
    }
#pragma unroll
    for (int off = 32; off; off >>= 1) {
        ca += __shfl_down(ca, off, 64);
        cb += __shfl_down(cb, off, 64);
        cw += __shfl_down(cw, off, 64);
    }
    if (lane == 0) {
        colv[r] = ca;       // raw x·Wa
        rowp[r] = cb;       // raw x·Wb  (relt added in pair path)
        cwv[r]  = cw;       // raw x·W1  (sigmoids applied in pair path)
    }
}

// ---------- launch 2: per-batch scalars (VERIFIED body, unchanged) ----------
__global__ void k_scalars(const float* __restrict__ relation, const float* __restrict__ subject,
                          const float* __restrict__ obj, const float* __restrict__ btheta,
                          const float* __restrict__ Wpair, const float* __restrict__ bpair,
                          const float* __restrict__ Wcls, const float* __restrict__ bcls,
                          const float* __restrict__ v,
                          float* __restrict__ relt, float* __restrict__ subc,
                          float* __restrict__ objc) {
    __shared__ float red[4];
    int wave = threadIdx.x >> 6, lane = threadIdx.x & 63;
    int b = blockIdx.x;
    const float4* aa;
    const float4* bb;
    if (wave == 0)      { aa = (const float4*)(relation + (size_t)b * DD); bb = (const float4*)v; }
    else if (wave == 1) { aa = (const float4*)(subject + (size_t)b * DD);  bb = (const float4*)(Wcls + DD); }
    else if (wave == 2) { aa = (const float4*)(obj + (size_t)b * DD);      bb = (const float4*)(Wcls + DD); }
    else                { aa = (const float4*)btheta;                      bb = (const float4*)(Wpair + 2 * DD); }
    float s = 0.f;
#pragma unroll
    for (int i = 0; i < 4; ++i) s += dot4(aa[i * 64 + lane], bb[i * 64 + lane]);
#pragma unroll
    for (int off = 32; off; off >>= 1) s += __shfl_down(s, off, 64);
    if (lane == 0) red[wave] = s;
    __syncthreads();
    if (threadIdx.x == 0) {
        relt[b] = red[0] + red[3] + bpair[0];
        subc[b] = red[1] + bcls[0];
        objc[b] = red[2] + bcls[0];
    }
}

// ---------- launch 3: fused bbox-GEMM (blocks 0..759) + pair/score/x_subj (760..2679) ----------
// GEMM path: VERBATIM R4/R6-verified 128x128 config (best measured 49.6us): bf16 A,
// XOR-swizzled LDS (conflicts=0), double-buffered, counted-vmcnt(8) barriers.
// Pair path: reads the 3 per-batch scalars from GLOBAL (computed by the verified
// k_scalars) and applies sigmoids + writes pair_score AND x_subj/x_obj. This differs
// from the failed R5 only by NOT recomputing scalars in-block.
#define BKK 64
#define NSTEP 16           // DD/BKK

#define WAITCNT_VM(N) asm volatile("s_waitcnt vmcnt(" #N ")" ::: "memory")

#define STAGE_TILE(buf, k0)                                                                  \
    _Pragma("unroll")                                                                        \
    for (int q = 0; q < 4; ++q) {                                                            \
        int rowblk = q * 32 + wave * 8;                                                      \
        const u16* ga = a_base + (size_t)(rowblk + s_row) * DD + (k0) + s_c16 * 8;           \
        __builtin_amdgcn_global_load_lds((const GLOBAL_AS unsigned int*)ga,                  \
                                         (LDS_AS unsigned int*)(As[buf] + rowblk * BKK),     \
                                         16, 0, 0);                                          \
        const u16* gb = b_base + (size_t)(rowblk + s_row) * DD + (k0) + s_c16 * 8;           \
        __builtin_amdgcn_global_load_lds((const GLOBAL_AS unsigned int*)gb,                  \
                                         (LDS_AS unsigned int*)(Bs[buf] + rowblk * BKK),     \
                                         16, 0, 0);                                          \
    }

#define COMPUTE_TILE(buf)                                                                    \
    _Pragma("unroll")                                                                        \
    for (int kk = 0; kk < BKK; kk += 32) {                                                   \
        bf16x8 af[4], bfv[4];                                                                \
        int cx = (((kk >> 3) + quad) ^ (l16 & 7)) * 8;                                       \
        _Pragma("unroll")                                                                    \
        for (int f = 0; f < 4; ++f) {                                                        \
            int m = wr * 64 + f * 16 + l16;                                                  \
            af[f] = *(const bf16x8*)(As[buf] + m * BKK + cx);                                \
            int n = wc * 64 + f * 16 + l16;                                                  \
            bfv[f] = *(const bf16x8*)(Bs[buf] + n * BKK + cx);                               \
        }                                                                                    \
        _Pragma("unroll")                                                                    \
        for (int fi = 0; fi < 4; ++fi)                                                       \
            _Pragma("unroll")                                                                \
            for (int fj = 0; fj < 4; ++fj)                                                   \
                acc[fi][fj] = __builtin_amdgcn_mfma_f32_16x16x32_bf16(                       \
                    af[fi], bfv[fj], acc[fi][fj], 0, 0, 0);                                  \
    }

__global__ __launch_bounds__(256) void k_fused(
        const u16* __restrict__ xb, const u16* __restrict__ bt,
        const float* __restrict__ bias, float* __restrict__ outb,
        const float* __restrict__ rowp, const float* __restrict__ colv,
        const float* __restrict__ cwv,
        const float* __restrict__ relt, const float* __restrict__ subc,
        const float* __restrict__ objc,
        float* __restrict__ outx, float* __restrict__ pout) {
    __shared__ u16 As[2][128 * BKK] __attribute__((aligned(16)));
    __shared__ u16 Bs[2][128 * BKK] __attribute__((aligned(16)));

    int gbid = blockIdx.x;
    if (gbid < 760) {
        // ---------------- GEMM path (verbatim R6) ----------------
        int xcd = gbid & 7;
        int rest = gbid >> 3;
        int n_t = rest % 5;
        int m_t = (rest / 5) * 8 + xcd;
        if (m_t >= 150) return;

        int tid = threadIdx.x;
        int wave = tid >> 6;
        int lane = tid & 63;
        int wr = wave >> 1, wc = wave & 1;
        int quad = lane >> 4;
        int l16 = lane & 15;

        f32x4 acc[4][4] = {};

        const u16* a_base = xb + (size_t)m_t * 128 * DD;
        const u16* b_base = bt + (size_t)n_t * 128 * DD;
        int s_row = lane >> 3;              // 0..7 (row within 8-row staging block)
        int s_c16 = (lane & 7) ^ s_row;     // pre-swizzled source 16B-chunk (XOR involution)

        STAGE_TILE(0, 0)

#pragma unroll 1
        for (int t = 0; t < NSTEP; t += 2) {
            // even half-step: stage t+1 into buf1; wait own old-8 (buf0) only; compute buf0
            STAGE_TILE(1, (t + 1) * BKK)
            WAITCNT_VM(8);
            __builtin_amdgcn_s_barrier();
            COMPUTE_TILE(0)
            __builtin_amdgcn_s_barrier();    // all waves done reading buf0
            // odd half-step: stage t+2 into buf0 (if any); wait buf1's loads; compute buf1
            if (t + 2 < NSTEP) {
                STAGE_TILE(0, (t + 2) * BKK)
                WAITCNT_VM(8);
            } else {
                WAITCNT_VM(0);
            }
            __builtin_amdgcn_s_barrier();
            COMPUTE_TILE(1)
            __builtin_amdgcn_s_barrier();
        }

        // epilogue: add bias, mask col<604, store fp32
#pragma unroll
        for (int fj = 0; fj < 4; ++fj) {
            int col = n_t * 128 + wc * 64 + fj * 16 + l16;
            if (col < NOUT) {
                float bia = bias[col];
#pragma unroll
                for (int fi = 0; fi < 4; ++fi) {
#pragma unroll
                    for (int rg = 0; rg < 4; ++rg) {
                        int row = m_t * 128 + wr * 64 + fi * 16 + quad * 4 + rg;
                        outb[(size_t)row * NOUT + col] = acc[fi][fj][rg] + bia;
                    }
                }
            }
        }
    } else {
        // ---------------- pair/score/x_subj path ----------------
        float* cb_s = (float*)As;            // colv panel [300]  (alias LDS; disjoint block path)
        float* ob_s = ((float*)As) + 300;    // o_score panel [300]
        float* cw_s = ((float*)As) + 600;    // xw panel [300]
        int blk = gbid - 760;                // 0..1919
        int b = blk / 30;
        int chunk = blk - b * 30;            // 0..29
        int r0 = b * 300 + chunk * 10;
        int tid = threadIdx.x;
        float relt_b = relt[b], subc_b = subc[b], objc_b = objc[b];
        for (int j = tid; j < 300; j += 256) {
            cb_s[j] = colv[b * 300 + j];
            float cwj = cwv[b * 300 + j];
            cw_s[j] = cwj;
            ob_s[j] = sigmoidf(cwj + objc_b);     // o_score[b][j]
        }
        __syncthreads();
        if (tid < 150) {
            float c0 = cb_s[2 * tid], c1 = cb_s[2 * tid + 1];
            float o0 = ob_s[2 * tid], o1 = ob_s[2 * tid + 1];
#pragma unroll
            for (int rr = 0; rr < 10; ++rr) {
                int r = r0 + rr;
                int lr = chunk * 10 + rr;
                float rp = rowp[r] + relt_b;              // row_term + rel_term
                float ss = sigmoidf(cw_s[lr] + subc_b);   // s_score[b][i]
                float p0 = sigmoidf(rp + c0) * o0 * ss;
                float p1 = sigmoidf(rp + c1) * o1 * ss;
                ((float2*)(pout + (size_t)r * 300))[tid] = make_float2(p0, p1);
            }
        } else if (tid < 160) {
            int rr = tid - 150;
            int r = r0 + rr;
            int lr = chunk * 10 + rr;
            float sv = sigmoidf(cw_s[lr] + subc_b);
            float ov = sigmoidf(cw_s[lr] + objc_b);
            ((float2*)outx)[r]         = make_float2(1.f - sv, sv);   // x_subj pair (fp32)
            ((float2*)outx)[NROWS + r] = make_float2(1.f - ov, ov);   // x_obj pair (fp32)
        }
    }
}

// ---------- fallback kernels (small workspace): previous verified path ----------
__global__ __launch_bounds__(256) void k_prep(const float* __restrict__ Wbbox, u16* __restrict__ Bt,
                                              const float* __restrict__ Wt, const float* __restrict__ Wpair,
                                              float* __restrict__ v) {
    __shared__ float tile[32][33];
    int blk = blockIdx.x;
    int tid = threadIdx.x;
    if (blk < 640) {
        int k0 = (blk & 31) * 32;
        int n0 = (blk >> 5) * 32;
        int tx = tid & 31;
        int ty = tid >> 5;
#pragma unroll
        for (int i = 0; i < 4; ++i) {
            int k = k0 + ty + i * 8;
            int n = n0 + tx;
            tile[ty + i * 8][tx] = (n < NOUT) ? Wbbox[(size_t)k * NOUT + n] : 0.f;
        }
        __syncthreads();
#pragma unroll
        for (int i = 0; i < 4; ++i) {
            int n = n0 + ty + i * 8;
            int k = k0 + tx;
            Bt[(size_t)n * DD + k] = f2bf(tile[tx][ty + i * 8]);
        }
    } else {
        int wave = tid >> 6, lane = tid & 63;
        int k = (blk - 640) * 4 + wave;
        const float4* row = (const float4*)(Wt + (size_t)k * DD);
        const float4* wc  = (const float4*)(Wpair + 2 * DD);
        float s = 0.f;
#pragma unroll
        for (int i = 0; i < 4; ++i) s += dot4(row[i * 64 + lane], wc[i * 64 + lane]);
#pragma unroll
        for (int off = 32; off; off >>= 1) s += __shfl_down(s, off, 64);
        if (lane == 0) v[k] = s;
    }
}

__global__ __launch_bounds__(256) void k_rows_sa(
        const float* __restrict__ x, const float* __restrict__ Wpair,
        const float* __restrict__ Wcls,
        const float* __restrict__ relt, const float* __restrict__ subc,
        const float* __restrict__ objc,
        float* __restrict__ colv, float* __restrict__ rowp,
        float* __restrict__ sarr, float* __restrict__ oarr,
        float* __restrict__ out) {
    int wave = threadIdx.x >> 6, lane = threadIdx.x & 63;
    int r = blockIdx.x * 4 + wave;                // 0..19199
    const float4* xr = (const float4*)(x + (size_t)r * DD);
    const float4* wa = (const float4*)(Wpair);
    const float4* wb = (const float4*)(Wpair + DD);
    const float4* w1 = (const float4*)(Wcls);
    float ca = 0.f, cb = 0.f, cw = 0.f;
#pragma unroll
    for (int i = 0; i < 4; ++i) {
        int idx = i * 64 + lane;
        float4 xv = xr[idx];
        ca += dot4(xv, wa[idx]);
        cb += dot4(xv, wb[idx]);
        cw += dot4(xv, w1[idx]);
    }
#pragma unroll
    for (int off = 32; off; off >>= 1) {
        ca += __shfl_down(ca, off, 64);
        cb += __shfl_down(cb, off, 64);
        cw += __shfl_down(cw, off, 64);
    }
    if (lane == 0) {
        int b = r / 300;
        float s = sigmoidf(cw + subc[b]);
        float o = sigmoidf(cw + objc[b]);
        colv[r] = ca;
        rowp[r] = cb + relt[b];
        sarr[r] = s;
        oarr[r] = o;
        ((float2*)out)[r]         = make_float2(1.f - s, s);
        ((float2*)out)[NROWS + r] = make_float2(1.f - o, o);
    }
}

__global__ __launch_bounds__(192) void k_pair_sa(
        const float* __restrict__ rowp, const float* __restrict__ colv,
        const float* __restrict__ sarr, const float* __restrict__ oarr,
        float* __restrict__ pout) {
    __shared__ float cb_s[300];
    __shared__ float ob_s[300];
    int blk = blockIdx.x;               // 0..1919
    int b = blk / 30;
    int chunk = blk - b * 30;           // 0..29
    int r0 = b * 300 + chunk * 10;
    int tid = threadIdx.x;
    for (int j = tid; j < 300; j += 192) {
        cb_s[j] = colv[b * 300 + j];
        ob_s[j] = oarr[b * 300 + j];
    }
    __syncthreads();
    if (tid < 150) {
        float c0 = cb_s[2 * tid], c1 = cb_s[2 * tid + 1];
        float o0 = ob_s[2 * tid], o1 = ob_s[2 * tid + 1];
#pragma unroll
        for (int rr = 0; rr < 10; ++rr) {
            int r = r0 + rr;
            float rp = rowp[r];
            float ss = sarr[r];
            float p0 = sigmoidf(rp + c0) * o0 * ss;
            float p1 = sigmoidf(rp + c1) * o1 * ss;
            ((float2*)(pout + (size_t)r * 300))[tid] = make_float2(p0, p1);
        }
    }
}

__global__ __launch_bounds__(256) void k_gemm(
        const float* __restrict__ x, const u16* __restrict__ bt,
        const float* __restrict__ bias, float* __restrict__ out) {
    __shared__ u16 As[128 * BKK] __attribute__((aligned(16)));
    __shared__ u16 Bs[128 * BKK] __attribute__((aligned(16)));

    int bid = blockIdx.x;
    int xcd = bid & 7;
    int rest = bid >> 3;
    int n_t = rest % 5;
    int m_t = (rest / 5) * 8 + xcd;
    if (m_t >= 150) return;

    int tid = threadIdx.x;
    int wave = tid >> 6;
    int lane = tid & 63;
    int wr = wave >> 1, wc = wave & 1;
    int quad = lane >> 4;
    int l16 = lane & 15;

    f32x4 acc[4][4] = {};

    const float* a_base = x  + (size_t)m_t * 128 * DD;
    const u16*   b_base = bt + (size_t)n_t * 128 * DD;
    int s_row = lane >> 3;
    int s_c16 = lane & 7;
    int arow8 = tid >> 4;
    int acol4 = tid & 15;

    for (int k0 = 0; k0 < DD; k0 += BKK) {
#pragma unroll
        for (int q = 0; q < 4; ++q) {
            int rowblk = q * 32 + wave * 8;
            const u16* gb = b_base + (size_t)(rowblk + s_row) * DD + k0 + s_c16 * 8;
            __builtin_amdgcn_global_load_lds((const GLOBAL_AS unsigned int*)gb,
                                             (LDS_AS unsigned int*)(Bs + rowblk * BKK),
                                             16, 0, 0);
        }
#pragma unroll
        for (int it = 0; it < 8; ++it) {
            int row = it * 16 + arow8;
            float4 av = *(const float4*)(a_base + (size_t)row * DD + k0 + acol4 * 4);
            unsigned lo = __builtin_amdgcn_perm(__float_as_uint(av.y), __float_as_uint(av.x), 0x07060302u);
            unsigned hi = __builtin_amdgcn_perm(__float_as_uint(av.w), __float_as_uint(av.z), 0x07060302u);
            *(uint2*)(As + row * BKK + acol4 * 4) = make_uint2(lo, hi);
        }
        __syncthreads();
#pragma unroll
        for (int kk = 0; kk < BKK; kk += 32) {
            bf16x8 af[4], bfv[4];
#pragma unroll
            for (int f = 0; f < 4; ++f) {
                int m = wr * 64 + f * 16 + l16;
                af[f] = *(const bf16x8*)(As + m * BKK + kk + quad * 8);
                int n = wc * 64 + f * 16 + l16;
                bfv[f] = *(const bf16x8*)(Bs + n * BKK + kk + quad * 8);
            }
#pragma unroll
            for (int fi = 0; fi < 4; ++fi)
#pragma unroll
                for (int fj = 0; fj < 4; ++fj)
                    acc[fi][fj] = __builtin_amdgcn_mfma_f32_16x16x32_bf16(
                        af[fi], bfv[fj], acc[fi][fj], 0, 0, 0);
        }
        __syncthreads();
    }

#pragma unroll
    for (int fj = 0; fj < 4; ++fj) {
        int col = n_t * 128 + wc * 64 + fj * 16 + l16;
        if (col < NOUT) {
            float bia = bias[col];
#pragma unroll
            for (int fi = 0; fi < 4; ++fi) {
#pragma unroll
                for (int rg = 0; rg < 4; ++rg) {
                    int row = m_t * 128 + wr * 64 + fi * 16 + quad * 4 + rg;
                    out[(size_t)row * NOUT + col] = acc[fi][fj][rg] + bia;
                }
            }
        }
    }
}

extern "C" void kernel_launch(void* const* d_in, const int* in_sizes, int n_in,
                              void* d_out, int out_size, void* d_ws, size_t ws_size,
                              hipStream_t stream) {
    // ---- input binding by element counts (proven equivalent to dict order) ----
    const void* P[12] = {};
    int sv[3] = {-1, -1, -1}; int nsv = 0;
    int sc[2] = {-1, -1};     int nsc = 0;
    for (int i = 0; i < n_in; ++i) {
        switch (in_sizes[i]) {
            case 19660800: P[0]  = d_in[i]; break;
            case 65536:    if (nsv < 3) sv[nsv++] = i; break;
            case 1048576:  P[4]  = d_in[i]; break;
            case 1024:     P[5]  = d_in[i]; break;
            case 3072:     P[6]  = d_in[i]; break;
            case 1:        if (nsc < 2) sc[nsc++] = i; break;
            case 2048:     P[8]  = d_in[i]; break;
            case 618496:   P[10] = d_in[i]; break;
            case 604:      P[11] = d_in[i]; break;
            default: break;
        }
    }
    bool alpha = (n_in == 12 && in_sizes[0] == 618496);
    if (alpha) {
        P[2] = d_in[sv[0]]; P[3] = d_in[sv[1]]; P[1] = d_in[sv[2]];
        P[9] = d_in[sc[0]]; P[7] = d_in[sc[1]];
    } else {
        P[1] = d_in[sv[0]]; P[2] = d_in[sv[1]]; P[3] = d_in[sv[2]];
        P[7] = d_in[sc[0]]; P[9] = d_in[sc[1]];
    }
    const float* x        = (const float*)P[0];
    const float* subject  = (const float*)P[1];
    const float* obj      = (const float*)P[2];
    const float* relation = (const float*)P[3];
    const float* W_theta  = (const float*)P[4];
    const float* b_theta  = (const float*)P[5];
    const float* W_pair   = (const float*)P[6];
    const float* b_pair   = (const float*)P[7];
    const float* W_cls    = (const float*)P[8];
    const float* b_cls    = (const float*)P[9];
    const float* W_bbox   = (const float*)P[10];
    const float* b_bbox   = (const float*)P[11];
    float* out = (float*)d_out;

    // ws layout
    char* ws = (char*)d_ws;
    float* v    = (float*)(ws + 0);         // 1024 f32
    float* relt = (float*)(ws + 4096);      // 64 f32
    float* subc = (float*)(ws + 4352);      // 64 f32
    float* objc = (float*)(ws + 4608);      // 64 f32
    float* colv = (float*)(ws + 4864);      // 19200 f32
    float* rowp = (float*)(ws + 81664);     // 19200 f32
    float* cwv  = (float*)(ws + 158464);    // 19200 f32 (big: raw cw; fallback: sarr)
    float* oarr = (float*)(ws + 235264);    // 19200 f32 (fallback only)
    u16*   Bt   = (u16*)(ws + 312064);      // 640*1024 bf16 = 1,310,720 B (end 1,622,784)
    u16*   Xb   = (u16*)(ws + 1622784);     // 19200*1024 bf16 = 39,321,600 B (end 40,944,384)

    const size_t WS_NEED_BF16 = 40944384;
    bool big_ws = (ws_size >= WS_NEED_BF16);

    if (big_ws) {
        // launch 1: rows-raw (4800) + transpose (640) + vtheta (256) — all independent
        k_rows_raw<<<5696, 256, 0, stream>>>(x, W_pair, W_cls, colv, rowp, cwv, Xb,
                                             W_bbox, Bt, W_theta, v);
        // launch 2: per-batch scalars (verified kernel)
        k_scalars<<<64, 256, 0, stream>>>(relation, subject, obj, b_theta, W_pair, b_pair,
                                          W_cls, b_cls, v, relt, subc, objc);
        // launch 3: GEMM + pair/x_subj
        k_fused<<<2680, 256, 0, stream>>>(Xb, Bt, b_bbox, out + OFF_BBOX,
                                          rowp, colv, cwv, relt, subc, objc,
                                          out, out + OFF_PAIR);
    } else {
        k_prep<<<896, 256, 0, stream>>>(W_bbox, Bt, W_theta, W_pair, v);
        k_scalars<<<64, 256, 0, stream>>>(relation, subject, obj, b_theta, W_pair, b_pair,
                                          W_cls, b_cls, v, relt, subc, objc);
        k_rows_sa<<<4800, 256, 0, stream>>>(x, W_pair, W_cls, relt, subc, objc,
                                            colv, rowp, cwv, oarr, out);
        k_pair_sa<<<1920, 192, 0, stream>>>(rowp, colv, cwv, oarr, out + OFF_PAIR);
        k_gemm<<<760, 256, 0, stream>>>(x, Bt, b_bbox, out + OFF_BBOX);
    }
}